// Round 13
// baseline (500.663 us; speedup 1.0000x reference)
//
#include <hip/hip_runtime.h>
#include <hip/hip_bf16.h>

#define B_ 2
#define T_ 2048
#define D_ 1024
#define H_ 16

typedef __attribute__((ext_vector_type(8))) short bf16x8;
typedef __attribute__((ext_vector_type(4))) float f32x4;

__device__ __forceinline__ unsigned pack_bf16(float x, float y) {
  unsigned xb = __float_as_uint(x), yb = __float_as_uint(y);
  xb += 0x7fffu + ((xb >> 16) & 1u);
  yb += 0x7fffu + ((yb >> 16) & 1u);
  return (xb >> 16) | (yb & 0xffff0000u);
}
__device__ __forceinline__ unsigned short f2b(float x) {
  unsigned u = __float_as_uint(x);
  u += 0x7fffu + ((u >> 16) & 1u);
  return (unsigned short)(u >> 16);
}
__device__ __forceinline__ float blo(unsigned u) { return __uint_as_float(u << 16); }
__device__ __forceinline__ float bhi(unsigned u) { return __uint_as_float(u & 0xffff0000u); }

__device__ __forceinline__ void gld_lds16(const unsigned short* g, unsigned short* l) {
  __builtin_amdgcn_global_load_lds(
      (const __attribute__((address_space(1))) unsigned int*)g,
      (__attribute__((address_space(3))) unsigned int*)l, 16, 0, 0);
}

// ---------- weight transpose + convert: Wt[n][k] = bf16(W[k][n]), 4 weights ----------
__global__ __launch_bounds__(256) void wtrans(const float* __restrict__ W0, const float* __restrict__ W1,
                                              const float* __restrict__ W2, const float* __restrict__ W3,
                                              unsigned short* __restrict__ T0, unsigned short* __restrict__ T1,
                                              unsigned short* __restrict__ T2, unsigned short* __restrict__ T3) {
  const int z = blockIdx.z;
  const float* W = z == 0 ? W0 : z == 1 ? W1 : z == 2 ? W2 : W3;
  unsigned short* T = z == 0 ? T0 : z == 1 ? T1 : z == 2 ? T2 : T3;
  __shared__ unsigned short t[64][72];
  const int k0 = blockIdx.x << 6, n0 = blockIdx.y << 6;
  const int r = threadIdx.x >> 2, c16 = (threadIdx.x & 3) << 4;
#pragma unroll
  for (int e = 0; e < 4; ++e) {
    const float4 v = *(const float4*)&W[(size_t)(k0 + r) * 1024 + n0 + c16 + e * 4];
    t[r][c16 + e * 4 + 0] = f2b(v.x);
    t[r][c16 + e * 4 + 1] = f2b(v.y);
    t[r][c16 + e * 4 + 2] = f2b(v.z);
    t[r][c16 + e * 4 + 3] = f2b(v.w);
  }
  __syncthreads();
  unsigned short o[16];
#pragma unroll
  for (int e = 0; e < 16; ++e) o[e] = t[c16 + e][r];
  unsigned short* dst = &T[(size_t)(n0 + r) * 1024 + k0 + c16];
  *(uint4*)&dst[0] = *(uint4*)&o[0];
  *(uint4*)&dst[8] = *(uint4*)&o[8];
}

// ---------- x fp32 -> bf16 ----------
__global__ __launch_bounds__(256) void xconv(const float* __restrict__ x, unsigned short* __restrict__ xb) {
  const int i = (blockIdx.x * 256 + threadIdx.x) * 8;
  const float4 a = *(const float4*)&x[i];
  const float4 b = *(const float4*)&x[i + 4];
  uint4 o;
  o.x = pack_bf16(a.x, a.y);
  o.y = pack_bf16(a.z, a.w);
  o.z = pack_bf16(b.x, b.y);
  o.w = pack_bf16(b.z, b.w);
  *(uint4*)&xb[i] = o;
}

// ---------- bf16 MFMA GEMM: Y = A[M,1024] @ Bt[n][k]^T + bias ----------
template <bool BF16OUT>
__global__ __launch_bounds__(256) void gemm_mfma(const unsigned short* __restrict__ A,
                                                 const unsigned short* __restrict__ B0,
                                                 const unsigned short* __restrict__ B1,
                                                 const unsigned short* __restrict__ B2,
                                                 const float* __restrict__ bi0, const float* __restrict__ bi1,
                                                 const float* __restrict__ bi2,
                                                 void* __restrict__ Y0, void* __restrict__ Y1,
                                                 void* __restrict__ Y2) {
  const int z = blockIdx.z;
  const unsigned short* Bt = z == 0 ? B0 : z == 1 ? B1 : B2;
  const float* bias = z == 0 ? bi0 : z == 1 ? bi1 : bi2;
  void* Y = z == 0 ? Y0 : z == 1 ? Y1 : Y2;
  __shared__ unsigned short As[8192];
  __shared__ unsigned short Bs[8192];
  const int tid = threadIdx.x;
  const int m0 = blockIdx.y << 7, n0 = blockIdx.x << 7;
  const int w = tid >> 6, l = tid & 63, g = l >> 4, c = l & 15;
  const int wm = (w >> 1) << 6, wn = (w & 1) << 6;
  const int srow = tid >> 3;
  const int skel = ((tid & 7) ^ (srow & 7)) << 3;
  const unsigned short* ga = &A[(size_t)(m0 + srow) * 1024 + skel];
  const unsigned short* gb = &Bt[(size_t)(n0 + srow) * 1024 + skel];
  unsigned short* la = &As[tid << 3];
  unsigned short* lb = &Bs[tid << 3];
  f32x4 acc[4][4];
#pragma unroll
  for (int i = 0; i < 4; ++i)
#pragma unroll
    for (int j = 0; j < 4; ++j) acc[i][j] = {0.f, 0.f, 0.f, 0.f};
  for (int k0 = 0; k0 < 1024; k0 += 64) {
    __syncthreads();
#pragma unroll
    for (int a = 0; a < 4; ++a) {
      gld_lds16(ga + (size_t)(a << 5) * 1024 + k0, la + (a << 11));
      gld_lds16(gb + (size_t)(a << 5) * 1024 + k0, lb + (a << 11));
    }
    __syncthreads();
#pragma unroll
    for (int kc = 0; kc < 2; ++kc) {
      bf16x8 af[4], bfr[4];
#pragma unroll
      for (int mf = 0; mf < 4; ++mf) {
        const int m = wm + (mf << 4) + c;
        af[mf] = *(const bf16x8*)&As[((m << 6) + (kc << 5) + (g << 3)) ^ ((m & 7) << 3)];
      }
#pragma unroll
      for (int nf = 0; nf < 4; ++nf) {
        const int n = wn + (nf << 4) + c;
        bfr[nf] = *(const bf16x8*)&Bs[((n << 6) + (kc << 5) + (g << 3)) ^ ((n & 7) << 3)];
      }
#pragma unroll
      for (int mf = 0; mf < 4; ++mf)
#pragma unroll
        for (int nf = 0; nf < 4; ++nf)
          acc[mf][nf] = __builtin_amdgcn_mfma_f32_16x16x32_bf16(af[mf], bfr[nf], acc[mf][nf], 0, 0, 0);
    }
  }
#pragma unroll
  for (int nf = 0; nf < 4; ++nf) {
    const int n = n0 + wn + (nf << 4) + c;
    const float bb = bias[n];
#pragma unroll
    for (int mf = 0; mf < 4; ++mf) {
      const int mrow = m0 + wm + (mf << 4) + (g << 2);
#pragma unroll
      for (int r = 0; r < 4; ++r) {
        const float val = acc[mf][nf][r] + bb;
        if (BF16OUT)
          ((unsigned short*)Y)[((size_t)(mrow + r) << 10) + n] = f2b(val);
        else
          ((float*)Y)[((size_t)(mrow + r) << 10) + n] = val;
      }
    }
  }
}

// ---------- bf16 transpose: Vb [b][t][d] -> Vt [b][d][t] ----------
__global__ __launch_bounds__(256) void transpose_bf16(const unsigned short* __restrict__ Vb,
                                                      unsigned short* __restrict__ Vt) {
  __shared__ unsigned short tile[64][73];
  const int b = blockIdx.z;
  const int t0 = blockIdx.x << 6, d0 = blockIdx.y << 6;
  const int row = threadIdx.x >> 2, cq = (threadIdx.x & 3) << 4;
  const unsigned short* src = &Vb[((size_t)((b << 11) + t0 + row) << 10) + d0 + cq];
  const uint4 va = *(const uint4*)&src[0];
  const uint4 vb2 = *(const uint4*)&src[8];
  const unsigned in[8] = {va.x, va.y, va.z, va.w, vb2.x, vb2.y, vb2.z, vb2.w};
#pragma unroll
  for (int e = 0; e < 8; ++e) {
    tile[row][cq + 2 * e] = (unsigned short)in[e];
    tile[row][cq + 2 * e + 1] = (unsigned short)(in[e] >> 16);
  }
  __syncthreads();
  unsigned o[8];
#pragma unroll
  for (int e = 0; e < 8; ++e)
    o[e] = (unsigned)tile[cq + 2 * e][row] | ((unsigned)tile[cq + 2 * e + 1][row] << 16);
  unsigned short* dst = &Vt[((size_t)((b << 10) + d0 + row) << 11) + t0 + cq];
  uint4 lo, hi;
  lo.x = o[0]; lo.y = o[1]; lo.z = o[2]; lo.w = o[3];
  hi.x = o[4]; hi.y = o[5]; hi.z = o[6]; hi.w = o[7];
  *(uint4*)&dst[0] = lo;
  *(uint4*)&dst[8] = hi;
}

// ---------- per-32-row block sums of V ----------
__global__ __launch_bounds__(256) void vblk32(const unsigned short* __restrict__ Vb,
                                              float* __restrict__ Blk) {
  const int b = blockIdx.x >> 6, t = blockIdx.x & 63;
  const int d4 = threadIdx.x << 2;
  float s0 = 0.f, s1 = 0.f, s2 = 0.f, s3 = 0.f;
  for (int j = 0; j < 32; ++j) {
    const uint2 v = *(const uint2*)&Vb[((size_t)((b << 11) + (t << 5) + j) << 10) + d4];
    s0 += blo(v.x); s1 += bhi(v.x); s2 += blo(v.y); s3 += bhi(v.y);
  }
  float4 o = {s0, s1, s2, s3};
  *(float4*)&Blk[((size_t)((b << 6) + t) << 10) + d4] = o;
}

// ---------- suffix over 64 tiles ----------
__global__ __launch_bounds__(256) void vsuffix32(const float* __restrict__ Blk, float* __restrict__ Suf) {
  const int idx = blockIdx.x * 256 + threadIdx.x;
  const int b = idx >> 10, d = idx & 1023;
  float s = 0.f;
  Suf[((size_t)(b * 65 + 64) << 10) + d] = 0.f;
  for (int t = 63; t >= 0; --t) {
    s += Blk[((size_t)((b << 6) + t) << 10) + d];
    Suf[((size_t)(b * 65 + t) << 10) + d] = s;
  }
}

// ---------- attn A: head-softmax denominators, R = 1/D as bf16 ----------
// Wave-unit (b,s,y,e): i-tile y, j-eighth (e ? 7-s : s). All 16 heads swept
// sequentially with a running Sigma-exp (no exchange, no LDS, no barriers).
__global__ __launch_bounds__(512, 4) void attn_denom(const unsigned short* __restrict__ Qb,
                                                     const unsigned short* __restrict__ Kb,
                                                     unsigned short* __restrict__ R0,
                                                     unsigned short* __restrict__ R1) {
  const int combo = blockIdx.x;
  const int b = combo & 1, s = combo >> 1;
  const int tid = threadIdx.x;
  const int w = tid >> 6, l = tid & 63, g = l >> 4, c = l & 15;
  const int u = blockIdx.y * 8 + w;  // 0..255
  const int y = 127 - (u >> 1);
  const int e = u & 1;
  const int eh = e ? (7 - s) : s;
  const int nt = (y + 2) >> 1;
  const int lo = eh << 3;
  if (lo >= nt) return;
  const int hi = (lo + 8) < nt ? (lo + 8) : nt;
  const int i0 = y << 4;
  const float SC = 0.04508422f;  // log2(e)/32
  unsigned short* Rb = b ? R1 : R0;
  const unsigned short* qrow = &Qb[((size_t)((b << 11) + i0 + c) << 10) + (g << 3)];
  unsigned short* rrow = &Rb[((size_t)(i0 + c) << 11) + (g << 2)];

  for (int ts = lo; ts < hi; ++ts) {
    const int j0 = ts << 5;
    const unsigned short* k0row = &Kb[((size_t)((b << 11) + j0 + c) << 10) + (g << 3)];
    const unsigned short* k1row = &Kb[((size_t)((b << 11) + j0 + 16 + c) << 10) + (g << 3)];
    f32x4 ps0 = {0.f, 0.f, 0.f, 0.f}, ps1 = {0.f, 0.f, 0.f, 0.f};
#pragma unroll 4
    for (int h = 0; h < 16; ++h) {
      const bf16x8 q0 = *(const bf16x8*)&qrow[h << 6];
      const bf16x8 q1 = *(const bf16x8*)&qrow[(h << 6) + 32];
      const bf16x8 ka0 = *(const bf16x8*)&k0row[h << 6];
      const bf16x8 ka1 = *(const bf16x8*)&k0row[(h << 6) + 32];
      const bf16x8 kb0 = *(const bf16x8*)&k1row[h << 6];
      const bf16x8 kb1 = *(const bf16x8*)&k1row[(h << 6) + 32];
      f32x4 a = {0.f, 0.f, 0.f, 0.f}, d = {0.f, 0.f, 0.f, 0.f};
      a = __builtin_amdgcn_mfma_f32_16x16x32_bf16(ka0, q0, a, 0, 0, 0);
      a = __builtin_amdgcn_mfma_f32_16x16x32_bf16(ka1, q1, a, 0, 0, 0);
      d = __builtin_amdgcn_mfma_f32_16x16x32_bf16(kb0, q0, d, 0, 0, 0);
      d = __builtin_amdgcn_mfma_f32_16x16x32_bf16(kb1, q1, d, 0, 0, 0);
#pragma unroll
      for (int r = 0; r < 4; ++r) {
        ps0[r] += exp2f(a[r] * SC);
        ps1[r] += exp2f(d[r] * SC);
      }
    }
    uint2 o0, o1;
    o0.x = pack_bf16(__builtin_amdgcn_rcpf(ps0[0]), __builtin_amdgcn_rcpf(ps0[1]));
    o0.y = pack_bf16(__builtin_amdgcn_rcpf(ps0[2]), __builtin_amdgcn_rcpf(ps0[3]));
    o1.x = pack_bf16(__builtin_amdgcn_rcpf(ps1[0]), __builtin_amdgcn_rcpf(ps1[1]));
    o1.y = pack_bf16(__builtin_amdgcn_rcpf(ps1[2]), __builtin_amdgcn_rcpf(ps1[3]));
    *(uint2*)&rrow[j0] = o0;
    *(uint2*)&rrow[j0 + 16] = o1;
  }
}

// ---------- attn B: fully independent PV waves (no LDS, no barriers) ----------
// Block = (b,s,y) with 8 waves = 8 head-pairs; strip s covers j-eighths {s,7-s}.
// Per 32-j step: V prefetch, QK mfma(K,Q) for 2 heads, exp2, read R (1/D) 8B,
// weights lane-local, PV. fp32 atomicAdd epilogue (AO pre-zeroed).
__global__ __launch_bounds__(512, 4) void attn_pv(const unsigned short* __restrict__ Qb,
                                                  const unsigned short* __restrict__ Kb,
                                                  const unsigned short* __restrict__ Vt,
                                                  const unsigned short* __restrict__ R0,
                                                  const unsigned short* __restrict__ R1,
                                                  float* __restrict__ AO) {
  const int combo = blockIdx.x;
  const int b = combo & 1, s = combo >> 1;
  const int y = 127 - blockIdx.y;  // heavy-first
  const int nt = (y + 2) >> 1;
  if (((s << 3) >= nt) && (((7 - s) << 3) >= nt)) return;
  const int i0 = y << 4;
  const int tid = threadIdx.x;
  const int hp = tid >> 6, l = tid & 63, g = l >> 4, c = l & 15;
  const int ib = i0 + c;
  const float SC = 0.04508422f;  // log2(e)/32

  const unsigned short* qbase = &Qb[((size_t)((b << 11) + i0 + c) << 10) + (hp << 7) + (g << 3)];
  bf16x8 qf[4];
  qf[0] = *(const bf16x8*)&qbase[0];
  qf[1] = *(const bf16x8*)&qbase[32];
  qf[2] = *(const bf16x8*)&qbase[64];
  qf[3] = *(const bf16x8*)&qbase[96];

  const unsigned short* Rb = b ? R1 : R0;
  const unsigned short* rrow = &Rb[((size_t)(i0 + c) << 11) + (g << 2)];
  const unsigned short* vb0 = &Vt[((size_t)((b << 10) + (hp << 7)) << 11)];

  f32x4 acc[2][4];
#pragma unroll
  for (int hh = 0; hh < 2; ++hh)
#pragma unroll
    for (int cc = 0; cc < 4; ++cc) acc[hh][cc] = {0.f, 0.f, 0.f, 0.f};

#pragma unroll
  for (int e = 0; e < 2; ++e) {
    const int eh = e ? (7 - s) : s;
    const int lo = eh << 3;
    const int hi = (lo + 8) < nt ? (lo + 8) : nt;
    for (int ts = lo; ts < hi; ++ts) {
      const int j0 = ts << 5;
      // V prefetch (independent; hides under QK + exp)
      uint2 vlo[2][4], vhi[2][4];
#pragma unroll
      for (int hh = 0; hh < 2; ++hh)
#pragma unroll
        for (int cc = 0; cc < 4; ++cc) {
          const unsigned short* vr =
              &vb0[((size_t)((hh << 6) + (cc << 4) + c) << 11) + j0 + (g << 2)];
          vlo[hh][cc] = *(const uint2*)&vr[0];
          vhi[hh][cc] = *(const uint2*)&vr[16];
        }
      // R read (8B per 16-j tile pair)
      const uint2 r0u = *(const uint2*)&rrow[j0];
      const uint2 r1u = *(const uint2*)&rrow[j0 + 16];
      // QK + exp
      f32x4 ex0[2], ex1[2];
#pragma unroll
      for (int jt = 0; jt < 2; ++jt) {
        const unsigned short* kbase =
            &Kb[((size_t)((b << 11) + j0 + (jt << 4) + c) << 10) + (hp << 7) + (g << 3)];
#pragma unroll
        for (int hh = 0; hh < 2; ++hh) {
          const bf16x8 k0 = *(const bf16x8*)&kbase[hh << 6];
          const bf16x8 k1 = *(const bf16x8*)&kbase[(hh << 6) + 32];
          f32x4 a = {0.f, 0.f, 0.f, 0.f};
          a = __builtin_amdgcn_mfma_f32_16x16x32_bf16(k0, qf[2 * hh], a, 0, 0, 0);
          a = __builtin_amdgcn_mfma_f32_16x16x32_bf16(k1, qf[2 * hh + 1], a, 0, 0, 0);
          f32x4 ex;
#pragma unroll
          for (int r = 0; r < 4; ++r) ex[r] = exp2f(a[r] * SC);
          if (jt == 0) ex0[hh] = ex;
          else ex1[hh] = ex;
        }
      }
      const f32x4 inv0 = {blo(r0u.x), bhi(r0u.x), blo(r0u.y), bhi(r0u.y)};
      const f32x4 inv1 = {blo(r1u.x), bhi(r1u.x), blo(r1u.y), bhi(r1u.y)};
      const int jb = j0 + (g << 2);
#pragma unroll
      for (int hh = 0; hh < 2; ++hh) {
        float w0[4], w1[4];
#pragma unroll
        for (int r = 0; r < 4; ++r) {
          w0[r] = (jb + r > ib) ? 0.0625f : ex0[hh][r] * inv0[r];
          w1[r] = (jb + 16 + r > ib) ? 0.0625f : ex1[hh][r] * inv1[r];
        }
        union { bf16x8 v; unsigned u[4]; } pa;
        pa.u[0] = pack_bf16(w0[0], w0[1]);
        pa.u[1] = pack_bf16(w0[2], w0[3]);
        pa.u[2] = pack_bf16(w1[0], w1[1]);
        pa.u[3] = pack_bf16(w1[2], w1[3]);
#pragma unroll
        for (int cc = 0; cc < 4; ++cc) {
          union { bf16x8 v; unsigned u[4]; } vf;
          vf.u[0] = vlo[hh][cc].x; vf.u[1] = vlo[hh][cc].y;
          vf.u[2] = vhi[hh][cc].x; vf.u[3] = vhi[hh][cc].y;
          acc[hh][cc] = __builtin_amdgcn_mfma_f32_16x16x32_bf16(pa.v, vf.v, acc[hh][cc], 0, 0, 0);
        }
      }
    }
  }
  // epilogue: atomic accumulate into fp32 AO
#pragma unroll
  for (int hh = 0; hh < 2; ++hh)
#pragma unroll
    for (int cc = 0; cc < 4; ++cc) {
      const int d = (hp << 7) + (hh << 6) + (cc << 4) + c;
#pragma unroll
      for (int r = 0; r < 4; ++r)
        atomicAdd(&AO[((size_t)((b << 11) + i0 + (g << 2) + r) << 10) + d], acc[hh][cc][r]);
    }
}

// ---------- AO fp32 + (1/16)*suffix -> bf16 ----------
__global__ __launch_bounds__(256) void aocvt(const float* __restrict__ AO, const float* __restrict__ Suf,
                                             unsigned short* __restrict__ AOb) {
  const int i = (blockIdx.x * 256 + threadIdx.x) << 3;
  const int m = i >> 10;
  const int b = m >> 11;
  const int sufidx = ((m & 2047) >> 5) + 1;
  const int d0 = i & 1023;
  const float* sp = &Suf[((size_t)(b * 65 + sufidx) << 10) + d0];
  const float4 a0 = *(const float4*)&AO[i];
  const float4 a1 = *(const float4*)&AO[i + 4];
  const float4 s0 = *(const float4*)&sp[0];
  const float4 s1 = *(const float4*)&sp[4];
  uint4 o;
  o.x = pack_bf16(a0.x + 0.0625f * s0.x, a0.y + 0.0625f * s0.y);
  o.y = pack_bf16(a0.z + 0.0625f * s0.z, a0.w + 0.0625f * s0.w);
  o.z = pack_bf16(a1.x + 0.0625f * s1.x, a1.y + 0.0625f * s1.y);
  o.w = pack_bf16(a1.z + 0.0625f * s1.z, a1.w + 0.0625f * s1.w);
  *(uint4*)&AOb[i] = o;
}

extern "C" void kernel_launch(void* const* d_in, const int* in_sizes, int n_in,
                              void* d_out, int out_size, void* d_ws, size_t ws_size,
                              hipStream_t stream) {
  (void)in_sizes; (void)n_in; (void)out_size; (void)ws_size;
  const float* x = (const float*)d_in[0];
  const float* Wq = (const float*)d_in[1];
  const float* bq = (const float*)d_in[2];
  const float* Wk = (const float*)d_in[3];
  const float* bk = (const float*)d_in[4];
  const float* Wv = (const float*)d_in[5];
  const float* bv = (const float*)d_in[6];
  const float* Wo = (const float*)d_in[7];
  const float* bo = (const float*)d_in[8];
  float* out = (float*)d_out;
  char* ws = (char*)d_ws;

  const size_t MB = 1024 * 1024;
  unsigned short* xb  = (unsigned short*)(ws);            // 0-8MB; = R0 after projections
  unsigned short* Qb  = (unsigned short*)(ws + 8 * MB);   // 8-16; = AOb after attn
  unsigned short* Kb  = (unsigned short*)(ws + 16 * MB);  // 16-24
  unsigned short* Vb  = (unsigned short*)(ws + 24 * MB);  // 24-32; = R1 after transpose+vblk
  unsigned short* Vt  = (unsigned short*)(ws + 32 * MB);  // 32-40
  unsigned short* Wqt = (unsigned short*)(ws + 40 * MB);  // 40-42; Blk/Suf overlay after proj
  unsigned short* Wkt = (unsigned short*)(ws + 42 * MB);  // 42-44
  unsigned short* Wvt = (unsigned short*)(ws + 44 * MB);  // 44-46
  unsigned short* Wot = (unsigned short*)(ws + 46 * MB);  // 46-48
  float* AO = (float*)(ws + 48 * MB);                     // 48-64: fp32 accumulation
  float* Blk = (float*)(ws + 40 * MB);
  float* Suf = (float*)(ws + 40 * MB + 512 * 1024);
  unsigned short* R0 = xb;
  unsigned short* R1 = Vb;
  unsigned short* AOb = Qb;

  hipLaunchKernelGGL(wtrans, dim3(16, 16, 4), dim3(256), 0, stream,
                     Wq, Wk, Wv, Wo, Wqt, Wkt, Wvt, Wot);
  hipLaunchKernelGGL(xconv, dim3(2048), dim3(256), 0, stream, x, xb);
  hipLaunchKernelGGL((gemm_mfma<true>), dim3(8, 32, 3), dim3(256), 0, stream,
                     xb, Wqt, Wkt, Wvt, bq, bk, bv, (void*)Qb, (void*)Kb, (void*)Vb);
  hipLaunchKernelGGL(transpose_bf16, dim3(32, 16, 2), dim3(256), 0, stream, Vb, Vt);
  hipLaunchKernelGGL(vblk32, dim3(128), dim3(256), 0, stream, Vb, Blk);
  hipLaunchKernelGGL(vsuffix32, dim3(8), dim3(256), 0, stream, Blk, Suf);
  hipMemsetAsync(AO, 0, (size_t)B_ * T_ * D_ * sizeof(float), stream);
  hipLaunchKernelGGL(attn_denom, dim3(8, 32), dim3(512), 0, stream, Qb, Kb, R0, R1);
  hipLaunchKernelGGL(attn_pv, dim3(8, 128), dim3(512), 0, stream, Qb, Kb, Vt, R0, R1, AO);
  hipLaunchKernelGGL(aocvt, dim3(2048), dim3(256), 0, stream, AO, Suf, AOb);
  hipLaunchKernelGGL((gemm_mfma<false>), dim3(8, 32, 1), dim3(256), 0, stream,
                     AOb, Wot, Wot, Wot, bo, bo, bo, (void*)out, (void*)out, (void*)out);
}

// Round 14
// 232.413 us; speedup vs baseline: 2.1542x; 2.1542x over previous
//
#include <hip/hip_runtime.h>
#include <hip/hip_bf16.h>

#define B_ 2
#define T_ 2048
#define D_ 1024
#define H_ 16

typedef __attribute__((ext_vector_type(8))) short bf16x8;
typedef __attribute__((ext_vector_type(4))) float f32x4;

__device__ __forceinline__ unsigned pack_bf16(float x, float y) {
  unsigned xb = __float_as_uint(x), yb = __float_as_uint(y);
  xb += 0x7fffu + ((xb >> 16) & 1u);
  yb += 0x7fffu + ((yb >> 16) & 1u);
  return (xb >> 16) | (yb & 0xffff0000u);
}
__device__ __forceinline__ unsigned short f2b(float x) {
  unsigned u = __float_as_uint(x);
  u += 0x7fffu + ((u >> 16) & 1u);
  return (unsigned short)(u >> 16);
}
__device__ __forceinline__ float blo(unsigned u) { return __uint_as_float(u << 16); }
__device__ __forceinline__ float bhi(unsigned u) { return __uint_as_float(u & 0xffff0000u); }

__device__ __forceinline__ void gld_lds16(const unsigned short* g, unsigned short* l) {
  __builtin_amdgcn_global_load_lds(
      (const __attribute__((address_space(1))) unsigned int*)g,
      (__attribute__((address_space(3))) unsigned int*)l, 16, 0, 0);
}

// ---------- weight transpose + convert: Wt[n][k] = bf16(W[k][n]), 4 weights ----------
__global__ __launch_bounds__(256) void wtrans(const float* __restrict__ W0, const float* __restrict__ W1,
                                              const float* __restrict__ W2, const float* __restrict__ W3,
                                              unsigned short* __restrict__ T0, unsigned short* __restrict__ T1,
                                              unsigned short* __restrict__ T2, unsigned short* __restrict__ T3) {
  const int z = blockIdx.z;
  const float* W = z == 0 ? W0 : z == 1 ? W1 : z == 2 ? W2 : W3;
  unsigned short* T = z == 0 ? T0 : z == 1 ? T1 : z == 2 ? T2 : T3;
  __shared__ unsigned short t[64][72];
  const int k0 = blockIdx.x << 6, n0 = blockIdx.y << 6;
  const int r = threadIdx.x >> 2, c16 = (threadIdx.x & 3) << 4;
#pragma unroll
  for (int e = 0; e < 4; ++e) {
    const float4 v = *(const float4*)&W[(size_t)(k0 + r) * 1024 + n0 + c16 + e * 4];
    t[r][c16 + e * 4 + 0] = f2b(v.x);
    t[r][c16 + e * 4 + 1] = f2b(v.y);
    t[r][c16 + e * 4 + 2] = f2b(v.z);
    t[r][c16 + e * 4 + 3] = f2b(v.w);
  }
  __syncthreads();
  unsigned short o[16];
#pragma unroll
  for (int e = 0; e < 16; ++e) o[e] = t[c16 + e][r];
  unsigned short* dst = &T[(size_t)(n0 + r) * 1024 + k0 + c16];
  *(uint4*)&dst[0] = *(uint4*)&o[0];
  *(uint4*)&dst[8] = *(uint4*)&o[8];
}

// ---------- x fp32 -> bf16 ----------
__global__ __launch_bounds__(256) void xconv(const float* __restrict__ x, unsigned short* __restrict__ xb) {
  const int i = (blockIdx.x * 256 + threadIdx.x) * 8;
  const float4 a = *(const float4*)&x[i];
  const float4 b = *(const float4*)&x[i + 4];
  uint4 o;
  o.x = pack_bf16(a.x, a.y);
  o.y = pack_bf16(a.z, a.w);
  o.z = pack_bf16(b.x, b.y);
  o.w = pack_bf16(b.z, b.w);
  *(uint4*)&xb[i] = o;
}

// ---------- bf16 MFMA GEMM: Y = A[M,1024] @ Bt[n][k]^T + bias ----------
template <bool BF16OUT>
__global__ __launch_bounds__(256) void gemm_mfma(const unsigned short* __restrict__ A,
                                                 const unsigned short* __restrict__ B0,
                                                 const unsigned short* __restrict__ B1,
                                                 const unsigned short* __restrict__ B2,
                                                 const float* __restrict__ bi0, const float* __restrict__ bi1,
                                                 const float* __restrict__ bi2,
                                                 void* __restrict__ Y0, void* __restrict__ Y1,
                                                 void* __restrict__ Y2) {
  const int z = blockIdx.z;
  const unsigned short* Bt = z == 0 ? B0 : z == 1 ? B1 : B2;
  const float* bias = z == 0 ? bi0 : z == 1 ? bi1 : bi2;
  void* Y = z == 0 ? Y0 : z == 1 ? Y1 : Y2;
  __shared__ unsigned short As[8192];
  __shared__ unsigned short Bs[8192];
  const int tid = threadIdx.x;
  const int m0 = blockIdx.y << 7, n0 = blockIdx.x << 7;
  const int w = tid >> 6, l = tid & 63, g = l >> 4, c = l & 15;
  const int wm = (w >> 1) << 6, wn = (w & 1) << 6;
  const int srow = tid >> 3;
  const int skel = ((tid & 7) ^ (srow & 7)) << 3;
  const unsigned short* ga = &A[(size_t)(m0 + srow) * 1024 + skel];
  const unsigned short* gb = &Bt[(size_t)(n0 + srow) * 1024 + skel];
  unsigned short* la = &As[tid << 3];
  unsigned short* lb = &Bs[tid << 3];
  f32x4 acc[4][4];
#pragma unroll
  for (int i = 0; i < 4; ++i)
#pragma unroll
    for (int j = 0; j < 4; ++j) acc[i][j] = {0.f, 0.f, 0.f, 0.f};
  for (int k0 = 0; k0 < 1024; k0 += 64) {
    __syncthreads();
#pragma unroll
    for (int a = 0; a < 4; ++a) {
      gld_lds16(ga + (size_t)(a << 5) * 1024 + k0, la + (a << 11));
      gld_lds16(gb + (size_t)(a << 5) * 1024 + k0, lb + (a << 11));
    }
    __syncthreads();
#pragma unroll
    for (int kc = 0; kc < 2; ++kc) {
      bf16x8 af[4], bfr[4];
#pragma unroll
      for (int mf = 0; mf < 4; ++mf) {
        const int m = wm + (mf << 4) + c;
        af[mf] = *(const bf16x8*)&As[((m << 6) + (kc << 5) + (g << 3)) ^ ((m & 7) << 3)];
      }
#pragma unroll
      for (int nf = 0; nf < 4; ++nf) {
        const int n = wn + (nf << 4) + c;
        bfr[nf] = *(const bf16x8*)&Bs[((n << 6) + (kc << 5) + (g << 3)) ^ ((n & 7) << 3)];
      }
#pragma unroll
      for (int mf = 0; mf < 4; ++mf)
#pragma unroll
        for (int nf = 0; nf < 4; ++nf)
          acc[mf][nf] = __builtin_amdgcn_mfma_f32_16x16x32_bf16(af[mf], bfr[nf], acc[mf][nf], 0, 0, 0);
    }
  }
#pragma unroll
  for (int nf = 0; nf < 4; ++nf) {
    const int n = n0 + wn + (nf << 4) + c;
    const float bb = bias[n];
#pragma unroll
    for (int mf = 0; mf < 4; ++mf) {
      const int mrow = m0 + wm + (mf << 4) + (g << 2);
#pragma unroll
      for (int r = 0; r < 4; ++r) {
        const float val = acc[mf][nf][r] + bb;
        if (BF16OUT)
          ((unsigned short*)Y)[((size_t)(mrow + r) << 10) + n] = f2b(val);
        else
          ((float*)Y)[((size_t)(mrow + r) << 10) + n] = val;
      }
    }
  }
}

// ---------- bf16 transpose: Vb [b][t][d] -> Vt [b][d][t] ----------
__global__ __launch_bounds__(256) void transpose_bf16(const unsigned short* __restrict__ Vb,
                                                      unsigned short* __restrict__ Vt) {
  __shared__ unsigned short tile[64][73];
  const int b = blockIdx.z;
  const int t0 = blockIdx.x << 6, d0 = blockIdx.y << 6;
  const int row = threadIdx.x >> 2, cq = (threadIdx.x & 3) << 4;
  const unsigned short* src = &Vb[((size_t)((b << 11) + t0 + row) << 10) + d0 + cq];
  const uint4 va = *(const uint4*)&src[0];
  const uint4 vb2 = *(const uint4*)&src[8];
  const unsigned in[8] = {va.x, va.y, va.z, va.w, vb2.x, vb2.y, vb2.z, vb2.w};
#pragma unroll
  for (int e = 0; e < 8; ++e) {
    tile[row][cq + 2 * e] = (unsigned short)in[e];
    tile[row][cq + 2 * e + 1] = (unsigned short)(in[e] >> 16);
  }
  __syncthreads();
  unsigned o[8];
#pragma unroll
  for (int e = 0; e < 8; ++e)
    o[e] = (unsigned)tile[cq + 2 * e][row] | ((unsigned)tile[cq + 2 * e + 1][row] << 16);
  unsigned short* dst = &Vt[((size_t)((b << 10) + d0 + row) << 11) + t0 + cq];
  uint4 lo, hi;
  lo.x = o[0]; lo.y = o[1]; lo.z = o[2]; lo.w = o[3];
  hi.x = o[4]; hi.y = o[5]; hi.z = o[6]; hi.w = o[7];
  *(uint4*)&dst[0] = lo;
  *(uint4*)&dst[8] = hi;
}

// ---------- per-32-row block sums of V ----------
__global__ __launch_bounds__(256) void vblk32(const unsigned short* __restrict__ Vb,
                                              float* __restrict__ Blk) {
  const int b = blockIdx.x >> 6, t = blockIdx.x & 63;
  const int d4 = threadIdx.x << 2;
  float s0 = 0.f, s1 = 0.f, s2 = 0.f, s3 = 0.f;
  for (int j = 0; j < 32; ++j) {
    const uint2 v = *(const uint2*)&Vb[((size_t)((b << 11) + (t << 5) + j) << 10) + d4];
    s0 += blo(v.x); s1 += bhi(v.x); s2 += blo(v.y); s3 += bhi(v.y);
  }
  float4 o = {s0, s1, s2, s3};
  *(float4*)&Blk[((size_t)((b << 6) + t) << 10) + d4] = o;
}

// ---------- suffix over 64 tiles ----------
__global__ __launch_bounds__(256) void vsuffix32(const float* __restrict__ Blk, float* __restrict__ Suf) {
  const int idx = blockIdx.x * 256 + threadIdx.x;
  const int b = idx >> 10, d = idx & 1023;
  float s = 0.f;
  Suf[((size_t)(b * 65 + 64) << 10) + d] = 0.f;
  for (int t = 63; t >= 0; --t) {
    s += Blk[((size_t)((b << 6) + t) << 10) + d];
    Suf[((size_t)(b * 65 + t) << 10) + d] = s;
  }
}

// ---------- attention v14: LDS-staged, coalesced, 16-wave blocks ----------
// Block = (b,strip,s-qpair): 1024 thr = 2 i-subtiles (16 rows each, adjacent -> equal
// step counts) x 8 head-pair waves. Per 32-j step: cooperative K (64KB, XOR-swizzled)
// + V^T (64KB, (d>>1)&3-swizzled) staging via global_load_lds (coalesced!), QK from
// LDS, Sigma-exp exchange via bf16-packed Sx (16KB), lane-local weights, PV from LDS.
// XCD-pinned combos (v12-verified), strips {s,7-s} exactly balanced (520 steps each).
__global__ __launch_bounds__(1024, 4) void attn_v14(const unsigned short* __restrict__ Qb,
                                                    const unsigned short* __restrict__ Kb,
                                                    const unsigned short* __restrict__ Vt,
                                                    unsigned short* __restrict__ P0,
                                                    unsigned short* __restrict__ P1,
                                                    unsigned short* __restrict__ P2,
                                                    unsigned short* __restrict__ P3) {
  __shared__ unsigned short Ks[32 * 1024];  // 64 KB
  __shared__ unsigned short Vs[1024 * 32];  // 64 KB
  __shared__ uint2 Sx[2][8][2][64];         // 16 KB (bf16-packed partial denominators)

  const int combo = blockIdx.x;
  const int b = combo & 1, s = combo >> 1;
  const int q = 63 - blockIdx.y;  // heavy-first; i-rows [32q, 32q+32)
  const int nt = q + 1;           // 32-j steps covering the pair's diagonal
  const int tid = threadIdx.x;
  const int w = tid >> 6, l = tid & 63, g = l >> 4, c = l & 15;
  const int isub = w >> 3, hp = w & 7;
  const int i0w = (q << 5) + (isub << 4);
  const int ib = i0w + c;
  const float SC = 0.04508422f;  // log2(e)/32

  // Q B-frags: own isub rows, own 2 heads (16 VGPR)
  const unsigned short* qbase = &Qb[((size_t)((b << 11) + i0w + c) << 10) + (hp << 7) + (g << 3)];
  bf16x8 qf[4];
  qf[0] = *(const bf16x8*)&qbase[0];
  qf[1] = *(const bf16x8*)&qbase[32];
  qf[2] = *(const bf16x8*)&qbase[64];
  qf[3] = *(const bf16x8*)&qbase[96];

  f32x4 acc[2][4];
#pragma unroll
  for (int hh = 0; hh < 2; ++hh)
#pragma unroll
    for (int cc = 0; cc < 4; ++cc) acc[hh][cc] = {0.f, 0.f, 0.f, 0.f};

#pragma unroll
  for (int e = 0; e < 2; ++e) {
    const int eh = e ? (7 - s) : s;
    const int lo = eh << 3;
    const int hi = (lo + 8) < nt ? (lo + 8) : nt;
    for (int ts = lo; ts < hi; ++ts) {
      const int j0 = ts << 5;
      __syncthreads();  // prior step's LDS reads complete
      // stage K[32][1024]: 4096 16B chunks, pre-swizzled source
#pragma unroll
      for (int kk = 0; kk < 4; ++kk) {
        const int qq = tid + (kk << 10);
        const int row = qq >> 7, cc8 = qq & 127;
        const int scc = cc8 ^ (row & 7);
        gld_lds16(&Kb[((size_t)((b << 11) + j0 + row) << 10) + (scc << 3)], &Ks[qq << 3]);
      }
      // stage V^T slice [1024 d][32 j]: 4096 16B chunks
#pragma unroll
      for (int kk = 0; kk < 4; ++kk) {
        const int qq = tid + (kk << 10);
        const int d = qq >> 2, jc = qq & 3;
        const int jcg = jc ^ ((d >> 1) & 3);
        gld_lds16(&Vt[(((size_t)((b << 10) + d)) << 11) + j0 + (jcg << 3)], &Vs[qq << 3]);
      }
      __syncthreads();  // staging complete (vmcnt drained by barrier)

      // QK from LDS + exp + Sx write
      f32x4 ex0[2], ex1[2];
      f32x4 ps0 = {0.f, 0.f, 0.f, 0.f}, ps1 = {0.f, 0.f, 0.f, 0.f};
      const int kx = c & 7;
#pragma unroll
      for (int jt = 0; jt < 2; ++jt) {
        const int krow = (jt << 4) + c;
#pragma unroll
        for (int hh = 0; hh < 2; ++hh) {
          const int e8 = ((hp << 1) + hh) << 3;
          const bf16x8 k0 = *(const bf16x8*)&Ks[((krow << 7) + ((e8 + g) ^ kx)) << 3];
          const bf16x8 k1 = *(const bf16x8*)&Ks[((krow << 7) + ((e8 + 4 + g) ^ kx)) << 3];
          f32x4 a = {0.f, 0.f, 0.f, 0.f};
          a = __builtin_amdgcn_mfma_f32_16x16x32_bf16(k0, qf[2 * hh], a, 0, 0, 0);
          a = __builtin_amdgcn_mfma_f32_16x16x32_bf16(k1, qf[2 * hh + 1], a, 0, 0, 0);
          f32x4 ex;
#pragma unroll
          for (int r = 0; r < 4; ++r) ex[r] = exp2f(a[r] * SC);
          if (jt == 0) { ex0[hh] = ex; ps0 += ex; }
          else { ex1[hh] = ex; ps1 += ex; }
        }
      }
      uint2 p0, p1;
      p0.x = pack_bf16(ps0[0], ps0[1]); p0.y = pack_bf16(ps0[2], ps0[3]);
      p1.x = pack_bf16(ps1[0], ps1[1]); p1.y = pack_bf16(ps1[2], ps1[3]);
      Sx[isub][hp][0][l] = p0;
      Sx[isub][hp][1][l] = p1;
      __syncthreads();  // Sx ready
      f32x4 s0 = {0.f, 0.f, 0.f, 0.f}, s1 = {0.f, 0.f, 0.f, 0.f};
#pragma unroll
      for (int d8 = 0; d8 < 8; ++d8) {
        const uint2 u0 = Sx[isub][d8][0][l];
        const uint2 u1 = Sx[isub][d8][1][l];
        s0[0] += blo(u0.x); s0[1] += bhi(u0.x); s0[2] += blo(u0.y); s0[3] += bhi(u0.y);
        s1[0] += blo(u1.x); s1[1] += bhi(u1.x); s1[2] += blo(u1.y); s1[3] += bhi(u1.y);
      }
      f32x4 inv0, inv1;
#pragma unroll
      for (int r = 0; r < 4; ++r) {
        inv0[r] = __builtin_amdgcn_rcpf(s0[r]);
        inv1[r] = __builtin_amdgcn_rcpf(s1[r]);
      }
      const int jb = j0 + (g << 2);
#pragma unroll
      for (int hh = 0; hh < 2; ++hh) {
        float w0[4], w1[4];
#pragma unroll
        for (int r = 0; r < 4; ++r) {
          w0[r] = (jb + r > ib) ? 0.0625f : ex0[hh][r] * inv0[r];
          w1[r] = (jb + 16 + r > ib) ? 0.0625f : ex1[hh][r] * inv1[r];
        }
        union { bf16x8 v; unsigned u[4]; } pa;
        pa.u[0] = pack_bf16(w0[0], w0[1]);
        pa.u[1] = pack_bf16(w0[2], w0[3]);
        pa.u[2] = pack_bf16(w1[0], w1[1]);
        pa.u[3] = pack_bf16(w1[2], w1[3]);
#pragma unroll
        for (int cc = 0; cc < 4; ++cc) {
          const int d = (((hp << 1) + hh) << 6) + (cc << 4) + c;
          const int sv = (d >> 1) & 3;
          const int sub = (g & 1) << 2;
          const uint2 lo8 = *(const uint2*)&Vs[((((d << 2) + ((g >> 1) ^ sv)) << 3)) + sub];
          const uint2 hi8 = *(const uint2*)&Vs[((((d << 2) + ((2 + (g >> 1)) ^ sv)) << 3)) + sub];
          union { bf16x8 v; unsigned u[4]; } vf;
          vf.u[0] = lo8.x; vf.u[1] = lo8.y;
          vf.u[2] = hi8.x; vf.u[3] = hi8.y;
          acc[hh][cc] = __builtin_amdgcn_mfma_f32_16x16x32_bf16(pa.v, vf.v, acc[hh][cc], 0, 0, 0);
        }
      }
    }
  }
  // write this (b, i-subtile) strip partial (zeros if strip had no steps)
  unsigned short* AOp = s == 0 ? P0 : s == 1 ? P1 : s == 2 ? P2 : P3;
#pragma unroll
  for (int hh = 0; hh < 2; ++hh)
#pragma unroll
    for (int cc = 0; cc < 4; ++cc) {
      const int d = (((hp << 1) + hh) << 6) + (cc << 4) + c;
#pragma unroll
      for (int r = 0; r < 4; ++r)
        AOp[((size_t)((b << 11) + i0w + (g << 2) + r) << 10) + d] = f2b(acc[hh][cc][r]);
    }
}

// ---------- sum 4 bf16 partials + (1/16)*suffix -> bf16 ----------
__global__ __launch_bounds__(256) void aocvt(const unsigned short* __restrict__ P0,
                                             const unsigned short* __restrict__ P1,
                                             const unsigned short* __restrict__ P2,
                                             const unsigned short* __restrict__ P3,
                                             const float* __restrict__ Suf,
                                             unsigned short* __restrict__ AOb) {
  const int i = (blockIdx.x * 256 + threadIdx.x) << 3;
  const int m = i >> 10;
  const int b = m >> 11;
  const int sufidx = ((m & 2047) >> 5) + 1;
  const int d0 = i & 1023;
  const float* sp = &Suf[((size_t)(b * 65 + sufidx) << 10) + d0];
  const uint4 v0 = *(const uint4*)&P0[i];
  const uint4 v1 = *(const uint4*)&P1[i];
  const uint4 v2 = *(const uint4*)&P2[i];
  const uint4 v3 = *(const uint4*)&P3[i];
  const float4 s0 = *(const float4*)&sp[0];
  const float4 s1 = *(const float4*)&sp[4];
  uint4 o;
  o.x = pack_bf16(blo(v0.x) + blo(v1.x) + blo(v2.x) + blo(v3.x) + 0.0625f * s0.x,
                  bhi(v0.x) + bhi(v1.x) + bhi(v2.x) + bhi(v3.x) + 0.0625f * s0.y);
  o.y = pack_bf16(blo(v0.y) + blo(v1.y) + blo(v2.y) + blo(v3.y) + 0.0625f * s0.z,
                  bhi(v0.y) + bhi(v1.y) + bhi(v2.y) + bhi(v3.y) + 0.0625f * s0.w);
  o.z = pack_bf16(blo(v0.z) + blo(v1.z) + blo(v2.z) + blo(v3.z) + 0.0625f * s1.x,
                  bhi(v0.z) + bhi(v1.z) + bhi(v2.z) + bhi(v3.z) + 0.0625f * s1.y);
  o.w = pack_bf16(blo(v0.w) + blo(v1.w) + blo(v2.w) + blo(v3.w) + 0.0625f * s1.z,
                  bhi(v0.w) + bhi(v1.w) + bhi(v2.w) + bhi(v3.w) + 0.0625f * s1.w);
  *(uint4*)&AOb[i] = o;
}

extern "C" void kernel_launch(void* const* d_in, const int* in_sizes, int n_in,
                              void* d_out, int out_size, void* d_ws, size_t ws_size,
                              hipStream_t stream) {
  (void)in_sizes; (void)n_in; (void)out_size; (void)ws_size;
  const float* x = (const float*)d_in[0];
  const float* Wq = (const float*)d_in[1];
  const float* bq = (const float*)d_in[2];
  const float* Wk = (const float*)d_in[3];
  const float* bk = (const float*)d_in[4];
  const float* Wv = (const float*)d_in[5];
  const float* bv = (const float*)d_in[6];
  const float* Wo = (const float*)d_in[7];
  const float* bo = (const float*)d_in[8];
  float* out = (float*)d_out;
  char* ws = (char*)d_ws;

  const size_t MB = 1024 * 1024;
  unsigned short* xb  = (unsigned short*)(ws);            // 0-8MB; = AOP0 after projections
  unsigned short* Qb  = (unsigned short*)(ws + 8 * MB);   // 8-16; = AOb after attn
  unsigned short* Kb  = (unsigned short*)(ws + 16 * MB);  // 16-24
  unsigned short* Vb  = (unsigned short*)(ws + 24 * MB);  // 24-32; = AOP1 after transpose/vblk
  unsigned short* Vt  = (unsigned short*)(ws + 32 * MB);  // 32-40
  unsigned short* Wqt = (unsigned short*)(ws + 40 * MB);  // 40-42; Blk/Suf overlay after proj
  unsigned short* Wkt = (unsigned short*)(ws + 42 * MB);  // 42-44
  unsigned short* Wvt = (unsigned short*)(ws + 44 * MB);  // 44-46
  unsigned short* Wot = (unsigned short*)(ws + 46 * MB);  // 46-48
  unsigned short* AOP2 = (unsigned short*)(ws + 48 * MB); // 48-56
  unsigned short* AOP3 = (unsigned short*)(ws + 56 * MB); // 56-64
  float* Blk = (float*)(ws + 40 * MB);
  float* Suf = (float*)(ws + 40 * MB + 512 * 1024);
  unsigned short* AOP0 = xb;
  unsigned short* AOP1 = Vb;
  unsigned short* AOb = Qb;

  hipLaunchKernelGGL(wtrans, dim3(16, 16, 4), dim3(256), 0, stream,
                     Wq, Wk, Wv, Wo, Wqt, Wkt, Wvt, Wot);
  hipLaunchKernelGGL(xconv, dim3(2048), dim3(256), 0, stream, x, xb);
  hipLaunchKernelGGL((gemm_mfma<true>), dim3(8, 32, 3), dim3(256), 0, stream,
                     xb, Wqt, Wkt, Wvt, bq, bk, bv, (void*)Qb, (void*)Kb, (void*)Vb);
  hipLaunchKernelGGL(transpose_bf16, dim3(32, 16, 2), dim3(256), 0, stream, Vb, Vt);
  hipLaunchKernelGGL(vblk32, dim3(128), dim3(256), 0, stream, Vb, Blk);
  hipLaunchKernelGGL(vsuffix32, dim3(8), dim3(256), 0, stream, Blk, Suf);
  hipLaunchKernelGGL(attn_v14, dim3(8, 64), dim3(1024), 0, stream,
                     Qb, Kb, Vt, AOP0, AOP1, AOP2, AOP3);
  hipLaunchKernelGGL(aocvt, dim3(2048), dim3(256), 0, stream,
                     AOP0, AOP1, AOP2, AOP3, Suf, AOb);
  hipLaunchKernelGGL((gemm_mfma<false>), dim3(8, 32, 1), dim3(256), 0, stream,
                     AOb, Wot, Wot, Wot, bo, bo, bo, (void*)out, (void*)out, (void*)out);
}

// Round 15
// 211.676 us; speedup vs baseline: 2.3652x; 1.0980x over previous
//
#include <hip/hip_runtime.h>
#include <hip/hip_bf16.h>

#define B_ 2
#define T_ 2048
#define D_ 1024
#define H_ 16

typedef __attribute__((ext_vector_type(8))) short bf16x8;
typedef __attribute__((ext_vector_type(4))) float f32x4;

__device__ __forceinline__ unsigned pack_bf16(float x, float y) {
  unsigned xb = __float_as_uint(x), yb = __float_as_uint(y);
  xb += 0x7fffu + ((xb >> 16) & 1u);
  yb += 0x7fffu + ((yb >> 16) & 1u);
  return (xb >> 16) | (yb & 0xffff0000u);
}
__device__ __forceinline__ unsigned short f2b(float x) {
  unsigned u = __float_as_uint(x);
  u += 0x7fffu + ((u >> 16) & 1u);
  return (unsigned short)(u >> 16);
}
__device__ __forceinline__ float blo(unsigned u) { return __uint_as_float(u << 16); }
__device__ __forceinline__ float bhi(unsigned u) { return __uint_as_float(u & 0xffff0000u); }

__device__ __forceinline__ void gld_lds16(const unsigned short* g, unsigned short* l) {
  __builtin_amdgcn_global_load_lds(
      (const __attribute__((address_space(1))) unsigned int*)g,
      (__attribute__((address_space(3))) unsigned int*)l, 16, 0, 0);
}

// ---------- weight transpose + convert: Wt[n][k] = bf16(W[k][n]), 4 weights ----------
__global__ __launch_bounds__(256) void wtrans(const float* __restrict__ W0, const float* __restrict__ W1,
                                              const float* __restrict__ W2, const float* __restrict__ W3,
                                              unsigned short* __restrict__ T0, unsigned short* __restrict__ T1,
                                              unsigned short* __restrict__ T2, unsigned short* __restrict__ T3) {
  const int z = blockIdx.z;
  const float* W = z == 0 ? W0 : z == 1 ? W1 : z == 2 ? W2 : W3;
  unsigned short* T = z == 0 ? T0 : z == 1 ? T1 : z == 2 ? T2 : T3;
  __shared__ unsigned short t[64][72];
  const int k0 = blockIdx.x << 6, n0 = blockIdx.y << 6;
  const int r = threadIdx.x >> 2, c16 = (threadIdx.x & 3) << 4;
#pragma unroll
  for (int e = 0; e < 4; ++e) {
    const float4 v = *(const float4*)&W[(size_t)(k0 + r) * 1024 + n0 + c16 + e * 4];
    t[r][c16 + e * 4 + 0] = f2b(v.x);
    t[r][c16 + e * 4 + 1] = f2b(v.y);
    t[r][c16 + e * 4 + 2] = f2b(v.z);
    t[r][c16 + e * 4 + 3] = f2b(v.w);
  }
  __syncthreads();
  unsigned short o[16];
#pragma unroll
  for (int e = 0; e < 16; ++e) o[e] = t[c16 + e][r];
  unsigned short* dst = &T[(size_t)(n0 + r) * 1024 + k0 + c16];
  *(uint4*)&dst[0] = *(uint4*)&o[0];
  *(uint4*)&dst[8] = *(uint4*)&o[8];
}

// ---------- x fp32 -> bf16 ----------
__global__ __launch_bounds__(256) void xconv(const float* __restrict__ x, unsigned short* __restrict__ xb) {
  const int i = (blockIdx.x * 256 + threadIdx.x) * 8;
  const float4 a = *(const float4*)&x[i];
  const float4 b = *(const float4*)&x[i + 4];
  uint4 o;
  o.x = pack_bf16(a.x, a.y);
  o.y = pack_bf16(a.z, a.w);
  o.z = pack_bf16(b.x, b.y);
  o.w = pack_bf16(b.z, b.w);
  *(uint4*)&xb[i] = o;
}

// ---------- bf16 MFMA GEMM: Y = A[M,1024] @ Bt[n][k]^T + bias ----------
template <bool BF16OUT>
__global__ __launch_bounds__(256) void gemm_mfma(const unsigned short* __restrict__ A,
                                                 const unsigned short* __restrict__ B0,
                                                 const unsigned short* __restrict__ B1,
                                                 const unsigned short* __restrict__ B2,
                                                 const float* __restrict__ bi0, const float* __restrict__ bi1,
                                                 const float* __restrict__ bi2,
                                                 void* __restrict__ Y0, void* __restrict__ Y1,
                                                 void* __restrict__ Y2) {
  const int z = blockIdx.z;
  const unsigned short* Bt = z == 0 ? B0 : z == 1 ? B1 : B2;
  const float* bias = z == 0 ? bi0 : z == 1 ? bi1 : bi2;
  void* Y = z == 0 ? Y0 : z == 1 ? Y1 : Y2;
  __shared__ unsigned short As[8192];
  __shared__ unsigned short Bs[8192];
  const int tid = threadIdx.x;
  const int m0 = blockIdx.y << 7, n0 = blockIdx.x << 7;
  const int w = tid >> 6, l = tid & 63, g = l >> 4, c = l & 15;
  const int wm = (w >> 1) << 6, wn = (w & 1) << 6;
  const int srow = tid >> 3;
  const int skel = ((tid & 7) ^ (srow & 7)) << 3;
  const unsigned short* ga = &A[(size_t)(m0 + srow) * 1024 + skel];
  const unsigned short* gb = &Bt[(size_t)(n0 + srow) * 1024 + skel];
  unsigned short* la = &As[tid << 3];
  unsigned short* lb = &Bs[tid << 3];
  f32x4 acc[4][4];
#pragma unroll
  for (int i = 0; i < 4; ++i)
#pragma unroll
    for (int j = 0; j < 4; ++j) acc[i][j] = {0.f, 0.f, 0.f, 0.f};
  for (int k0 = 0; k0 < 1024; k0 += 64) {
    __syncthreads();
#pragma unroll
    for (int a = 0; a < 4; ++a) {
      gld_lds16(ga + (size_t)(a << 5) * 1024 + k0, la + (a << 11));
      gld_lds16(gb + (size_t)(a << 5) * 1024 + k0, lb + (a << 11));
    }
    __syncthreads();
#pragma unroll
    for (int kc = 0; kc < 2; ++kc) {
      bf16x8 af[4], bfr[4];
#pragma unroll
      for (int mf = 0; mf < 4; ++mf) {
        const int m = wm + (mf << 4) + c;
        af[mf] = *(const bf16x8*)&As[((m << 6) + (kc << 5) + (g << 3)) ^ ((m & 7) << 3)];
      }
#pragma unroll
      for (int nf = 0; nf < 4; ++nf) {
        const int n = wn + (nf << 4) + c;
        bfr[nf] = *(const bf16x8*)&Bs[((n << 6) + (kc << 5) + (g << 3)) ^ ((n & 7) << 3)];
      }
#pragma unroll
      for (int mf = 0; mf < 4; ++mf)
#pragma unroll
        for (int nf = 0; nf < 4; ++nf)
          acc[mf][nf] = __builtin_amdgcn_mfma_f32_16x16x32_bf16(af[mf], bfr[nf], acc[mf][nf], 0, 0, 0);
    }
  }
#pragma unroll
  for (int nf = 0; nf < 4; ++nf) {
    const int n = n0 + wn + (nf << 4) + c;
    const float bb = bias[n];
#pragma unroll
    for (int mf = 0; mf < 4; ++mf) {
      const int mrow = m0 + wm + (mf << 4) + (g << 2);
#pragma unroll
      for (int r = 0; r < 4; ++r) {
        const float val = acc[mf][nf][r] + bb;
        if (BF16OUT)
          ((unsigned short*)Y)[((size_t)(mrow + r) << 10) + n] = f2b(val);
        else
          ((float*)Y)[((size_t)(mrow + r) << 10) + n] = val;
      }
    }
  }
}

// ---------- bf16 transpose: Vb [b][t][d] -> Vt [b][d][t] ----------
__global__ __launch_bounds__(256) void transpose_bf16(const unsigned short* __restrict__ Vb,
                                                      unsigned short* __restrict__ Vt) {
  __shared__ unsigned short tile[64][73];
  const int b = blockIdx.z;
  const int t0 = blockIdx.x << 6, d0 = blockIdx.y << 6;
  const int row = threadIdx.x >> 2, cq = (threadIdx.x & 3) << 4;
  const unsigned short* src = &Vb[((size_t)((b << 11) + t0 + row) << 10) + d0 + cq];
  const uint4 va = *(const uint4*)&src[0];
  const uint4 vb2 = *(const uint4*)&src[8];
  const unsigned in[8] = {va.x, va.y, va.z, va.w, vb2.x, vb2.y, vb2.z, vb2.w};
#pragma unroll
  for (int e = 0; e < 8; ++e) {
    tile[row][cq + 2 * e] = (unsigned short)in[e];
    tile[row][cq + 2 * e + 1] = (unsigned short)(in[e] >> 16);
  }
  __syncthreads();
  unsigned o[8];
#pragma unroll
  for (int e = 0; e < 8; ++e)
    o[e] = (unsigned)tile[cq + 2 * e][row] | ((unsigned)tile[cq + 2 * e + 1][row] << 16);
  unsigned short* dst = &Vt[((size_t)((b << 10) + d0 + row) << 11) + t0 + cq];
  uint4 lo, hi;
  lo.x = o[0]; lo.y = o[1]; lo.z = o[2]; lo.w = o[3];
  hi.x = o[4]; hi.y = o[5]; hi.z = o[6]; hi.w = o[7];
  *(uint4*)&dst[0] = lo;
  *(uint4*)&dst[8] = hi;
}

// ---------- per-32-row block sums of V ----------
__global__ __launch_bounds__(256) void vblk32(const unsigned short* __restrict__ Vb,
                                              float* __restrict__ Blk) {
  const int b = blockIdx.x >> 6, t = blockIdx.x & 63;
  const int d4 = threadIdx.x << 2;
  float s0 = 0.f, s1 = 0.f, s2 = 0.f, s3 = 0.f;
  for (int j = 0; j < 32; ++j) {
    const uint2 v = *(const uint2*)&Vb[((size_t)((b << 11) + (t << 5) + j) << 10) + d4];
    s0 += blo(v.x); s1 += bhi(v.x); s2 += blo(v.y); s3 += bhi(v.y);
  }
  float4 o = {s0, s1, s2, s3};
  *(float4*)&Blk[((size_t)((b << 6) + t) << 10) + d4] = o;
}

// ---------- suffix over 64 tiles ----------
__global__ __launch_bounds__(256) void vsuffix32(const float* __restrict__ Blk, float* __restrict__ Suf) {
  const int idx = blockIdx.x * 256 + threadIdx.x;
  const int b = idx >> 10, d = idx & 1023;
  float s = 0.f;
  Suf[((size_t)(b * 65 + 64) << 10) + d] = 0.f;
  for (int t = 63; t >= 0; --t) {
    s += Blk[((size_t)((b << 6) + t) << 10) + d];
    Suf[((size_t)(b * 65 + t) << 10) + d] = s;
  }
}

// ---------- attention v15: v14 staging + complementary q-pairing ----------
// Block = (b,strip,qpair): 1024 thr = 2 i-subtiles x 8 head-pair waves. Each block
// processes TWO 32-row q-tiles (q, 63-q) sequentially -> 16-17 steps for EVERY block
// (arithmetically constant). Grid 8x32 = 256 blocks = exactly 1/CU, one balanced round.
// Per 32-j step identical to v14: cooperative K/V staging (swizzled global_load_lds),
// QK from LDS, bf16 Sx exchange, lane-local weights, PV from LDS. Strip partials.
__global__ __launch_bounds__(1024, 4) void attn_v15(const unsigned short* __restrict__ Qb,
                                                    const unsigned short* __restrict__ Kb,
                                                    const unsigned short* __restrict__ Vt,
                                                    unsigned short* __restrict__ P0,
                                                    unsigned short* __restrict__ P1,
                                                    unsigned short* __restrict__ P2,
                                                    unsigned short* __restrict__ P3) {
  __shared__ unsigned short Ks[32 * 1024];  // 64 KB
  __shared__ unsigned short Vs[1024 * 32];  // 64 KB
  __shared__ uint2 Sx[2][8][2][64];         // 16 KB (bf16-packed partial denominators)

  const int combo = blockIdx.x;
  const int b = combo & 1, s = combo >> 1;
  const int qy = 63 - blockIdx.y;  // 32..63 (heavy phase first)
  const int tid = threadIdx.x;
  const int w = tid >> 6, l = tid & 63, g = l >> 4, c = l & 15;
  const int isub = w >> 3, hp = w & 7;
  const float SC = 0.04508422f;  // log2(e)/32
  unsigned short* AOp = s == 0 ? P0 : s == 1 ? P1 : s == 2 ? P2 : P3;

#pragma unroll
  for (int ph = 0; ph < 2; ++ph) {
    const int q = ph ? (63 - qy) : qy;
    const int nt = q + 1;            // 32-j steps covering this pair-tile's diagonal
    const int i0w = (q << 5) + (isub << 4);
    const int ib = i0w + c;

    // Q B-frags: own isub rows, own 2 heads (16 VGPR)
    const unsigned short* qbase =
        &Qb[((size_t)((b << 11) + i0w + c) << 10) + (hp << 7) + (g << 3)];
    bf16x8 qf[4];
    qf[0] = *(const bf16x8*)&qbase[0];
    qf[1] = *(const bf16x8*)&qbase[32];
    qf[2] = *(const bf16x8*)&qbase[64];
    qf[3] = *(const bf16x8*)&qbase[96];

    f32x4 acc[2][4];
#pragma unroll
    for (int hh = 0; hh < 2; ++hh)
#pragma unroll
      for (int cc = 0; cc < 4; ++cc) acc[hh][cc] = {0.f, 0.f, 0.f, 0.f};

#pragma unroll
    for (int e = 0; e < 2; ++e) {
      const int eh = e ? (7 - s) : s;
      const int lo = eh << 3;
      const int hi = (lo + 8) < nt ? (lo + 8) : nt;
      for (int ts = lo; ts < hi; ++ts) {
        const int j0 = ts << 5;
        __syncthreads();  // prior step's LDS reads complete
        // stage K[32][1024]: 4096 16B chunks, pre-swizzled source
#pragma unroll
        for (int kk = 0; kk < 4; ++kk) {
          const int qq = tid + (kk << 10);
          const int row = qq >> 7, cc8 = qq & 127;
          const int scc = cc8 ^ (row & 7);
          gld_lds16(&Kb[((size_t)((b << 11) + j0 + row) << 10) + (scc << 3)], &Ks[qq << 3]);
        }
        // stage V^T slice [1024 d][32 j]: 4096 16B chunks
#pragma unroll
        for (int kk = 0; kk < 4; ++kk) {
          const int qq = tid + (kk << 10);
          const int d = qq >> 2, jc = qq & 3;
          const int jcg = jc ^ ((d >> 1) & 3);
          gld_lds16(&Vt[(((size_t)((b << 10) + d)) << 11) + j0 + (jcg << 3)], &Vs[qq << 3]);
        }
        __syncthreads();  // staging complete

        // QK from LDS + exp + Sx write
        f32x4 ex0[2], ex1[2];
        f32x4 ps0 = {0.f, 0.f, 0.f, 0.f}, ps1 = {0.f, 0.f, 0.f, 0.f};
        const int kx = c & 7;
#pragma unroll
        for (int jt = 0; jt < 2; ++jt) {
          const int krow = (jt << 4) + c;
#pragma unroll
          for (int hh = 0; hh < 2; ++hh) {
            const int e8 = ((hp << 1) + hh) << 3;
            const bf16x8 k0 = *(const bf16x8*)&Ks[((krow << 7) + ((e8 + g) ^ kx)) << 3];
            const bf16x8 k1 = *(const bf16x8*)&Ks[((krow << 7) + ((e8 + 4 + g) ^ kx)) << 3];
            f32x4 a = {0.f, 0.f, 0.f, 0.f};
            a = __builtin_amdgcn_mfma_f32_16x16x32_bf16(k0, qf[2 * hh], a, 0, 0, 0);
            a = __builtin_amdgcn_mfma_f32_16x16x32_bf16(k1, qf[2 * hh + 1], a, 0, 0, 0);
            f32x4 ex;
#pragma unroll
            for (int r = 0; r < 4; ++r) ex[r] = exp2f(a[r] * SC);
            if (jt == 0) { ex0[hh] = ex; ps0 += ex; }
            else { ex1[hh] = ex; ps1 += ex; }
          }
        }
        uint2 p0, p1;
        p0.x = pack_bf16(ps0[0], ps0[1]); p0.y = pack_bf16(ps0[2], ps0[3]);
        p1.x = pack_bf16(ps1[0], ps1[1]); p1.y = pack_bf16(ps1[2], ps1[3]);
        Sx[isub][hp][0][l] = p0;
        Sx[isub][hp][1][l] = p1;
        __syncthreads();  // Sx ready
        f32x4 s0 = {0.f, 0.f, 0.f, 0.f}, s1 = {0.f, 0.f, 0.f, 0.f};
#pragma unroll
        for (int d8 = 0; d8 < 8; ++d8) {
          const uint2 u0 = Sx[isub][d8][0][l];
          const uint2 u1 = Sx[isub][d8][1][l];
          s0[0] += blo(u0.x); s0[1] += bhi(u0.x); s0[2] += blo(u0.y); s0[3] += bhi(u0.y);
          s1[0] += blo(u1.x); s1[1] += bhi(u1.x); s1[2] += blo(u1.y); s1[3] += bhi(u1.y);
        }
        f32x4 inv0, inv1;
#pragma unroll
        for (int r = 0; r < 4; ++r) {
          inv0[r] = __builtin_amdgcn_rcpf(s0[r]);
          inv1[r] = __builtin_amdgcn_rcpf(s1[r]);
        }
        const int jb = j0 + (g << 2);
#pragma unroll
        for (int hh = 0; hh < 2; ++hh) {
          float w0[4], w1[4];
#pragma unroll
          for (int r = 0; r < 4; ++r) {
            w0[r] = (jb + r > ib) ? 0.0625f : ex0[hh][r] * inv0[r];
            w1[r] = (jb + 16 + r > ib) ? 0.0625f : ex1[hh][r] * inv1[r];
          }
          union { bf16x8 v; unsigned u[4]; } pa;
          pa.u[0] = pack_bf16(w0[0], w0[1]);
          pa.u[1] = pack_bf16(w0[2], w0[3]);
          pa.u[2] = pack_bf16(w1[0], w1[1]);
          pa.u[3] = pack_bf16(w1[2], w1[3]);
#pragma unroll
          for (int cc = 0; cc < 4; ++cc) {
            const int d = (((hp << 1) + hh) << 6) + (cc << 4) + c;
            const int sv = (d >> 1) & 3;
            const int sub = (g & 1) << 2;
            const uint2 lo8 = *(const uint2*)&Vs[((((d << 2) + ((g >> 1) ^ sv)) << 3)) + sub];
            const uint2 hi8 = *(const uint2*)&Vs[((((d << 2) + ((2 + (g >> 1)) ^ sv)) << 3)) + sub];
            union { bf16x8 v; unsigned u[4]; } vf;
            vf.u[0] = lo8.x; vf.u[1] = lo8.y;
            vf.u[2] = hi8.x; vf.u[3] = hi8.y;
            acc[hh][cc] = __builtin_amdgcn_mfma_f32_16x16x32_bf16(pa.v, vf.v, acc[hh][cc], 0, 0, 0);
          }
        }
      }
    }
    // write this (b, i-subtile) strip partial (zeros where strip had no steps)
#pragma unroll
    for (int hh = 0; hh < 2; ++hh)
#pragma unroll
      for (int cc = 0; cc < 4; ++cc) {
        const int d = (((hp << 1) + hh) << 6) + (cc << 4) + c;
#pragma unroll
        for (int r = 0; r < 4; ++r)
          AOp[((size_t)((b << 11) + i0w + (g << 2) + r) << 10) + d] = f2b(acc[hh][cc][r]);
      }
    __syncthreads();  // all LDS/Sx reads of this phase done before next phase staging
  }
}

// ---------- sum 4 bf16 partials + (1/16)*suffix -> bf16 ----------
__global__ __launch_bounds__(256) void aocvt(const unsigned short* __restrict__ P0,
                                             const unsigned short* __restrict__ P1,
                                             const unsigned short* __restrict__ P2,
                                             const unsigned short* __restrict__ P3,
                                             const float* __restrict__ Suf,
                                             unsigned short* __restrict__ AOb) {
  const int i = (blockIdx.x * 256 + threadIdx.x) << 3;
  const int m = i >> 10;
  const int b = m >> 11;
  const int sufidx = ((m & 2047) >> 5) + 1;
  const int d0 = i & 1023;
  const float* sp = &Suf[((size_t)(b * 65 + sufidx) << 10) + d0];
  const uint4 v0 = *(const uint4*)&P0[i];
  const uint4 v1 = *(const uint4*)&P1[i];
  const uint4 v2 = *(const uint4*)&P2[i];
  const uint4 v3 = *(const uint4*)&P3[i];
  const float4 s0 = *(const float4*)&sp[0];
  const float4 s1 = *(const float4*)&sp[4];
  uint4 o;
  o.x = pack_bf16(blo(v0.x) + blo(v1.x) + blo(v2.x) + blo(v3.x) + 0.0625f * s0.x,
                  bhi(v0.x) + bhi(v1.x) + bhi(v2.x) + bhi(v3.x) + 0.0625f * s0.y);
  o.y = pack_bf16(blo(v0.y) + blo(v1.y) + blo(v2.y) + blo(v3.y) + 0.0625f * s0.z,
                  bhi(v0.y) + bhi(v1.y) + bhi(v2.y) + bhi(v3.y) + 0.0625f * s0.w);
  o.z = pack_bf16(blo(v0.z) + blo(v1.z) + blo(v2.z) + blo(v3.z) + 0.0625f * s1.x,
                  bhi(v0.z) + bhi(v1.z) + bhi(v2.z) + bhi(v3.z) + 0.0625f * s1.y);
  o.w = pack_bf16(blo(v0.w) + blo(v1.w) + blo(v2.w) + blo(v3.w) + 0.0625f * s1.z,
                  bhi(v0.w) + bhi(v1.w) + bhi(v2.w) + bhi(v3.w) + 0.0625f * s1.w);
  *(uint4*)&AOb[i] = o;
}

extern "C" void kernel_launch(void* const* d_in, const int* in_sizes, int n_in,
                              void* d_out, int out_size, void* d_ws, size_t ws_size,
                              hipStream_t stream) {
  (void)in_sizes; (void)n_in; (void)out_size; (void)ws_size;
  const float* x = (const float*)d_in[0];
  const float* Wq = (const float*)d_in[1];
  const float* bq = (const float*)d_in[2];
  const float* Wk = (const float*)d_in[3];
  const float* bk = (const float*)d_in[4];
  const float* Wv = (const float*)d_in[5];
  const float* bv = (const float*)d_in[6];
  const float* Wo = (const float*)d_in[7];
  const float* bo = (const float*)d_in[8];
  float* out = (float*)d_out;
  char* ws = (char*)d_ws;

  const size_t MB = 1024 * 1024;
  unsigned short* xb  = (unsigned short*)(ws);            // 0-8MB; = AOP0 after projections
  unsigned short* Qb  = (unsigned short*)(ws + 8 * MB);   // 8-16; = AOb after attn
  unsigned short* Kb  = (unsigned short*)(ws + 16 * MB);  // 16-24
  unsigned short* Vb  = (unsigned short*)(ws + 24 * MB);  // 24-32; = AOP1 after transpose/vblk
  unsigned short* Vt  = (unsigned short*)(ws + 32 * MB);  // 32-40
  unsigned short* Wqt = (unsigned short*)(ws + 40 * MB);  // 40-42; Blk/Suf overlay after proj
  unsigned short* Wkt = (unsigned short*)(ws + 42 * MB);  // 42-44
  unsigned short* Wvt = (unsigned short*)(ws + 44 * MB);  // 44-46
  unsigned short* Wot = (unsigned short*)(ws + 46 * MB);  // 46-48
  unsigned short* AOP2 = (unsigned short*)(ws + 48 * MB); // 48-56
  unsigned short* AOP3 = (unsigned short*)(ws + 56 * MB); // 56-64
  float* Blk = (float*)(ws + 40 * MB);
  float* Suf = (float*)(ws + 40 * MB + 512 * 1024);
  unsigned short* AOP0 = xb;
  unsigned short* AOP1 = Vb;
  unsigned short* AOb = Qb;

  hipLaunchKernelGGL(wtrans, dim3(16, 16, 4), dim3(256), 0, stream,
                     Wq, Wk, Wv, Wo, Wqt, Wkt, Wvt, Wot);
  hipLaunchKernelGGL(xconv, dim3(2048), dim3(256), 0, stream, x, xb);
  hipLaunchKernelGGL((gemm_mfma<true>), dim3(8, 32, 3), dim3(256), 0, stream,
                     xb, Wqt, Wkt, Wvt, bq, bk, bv, (void*)Qb, (void*)Kb, (void*)Vb);
  hipLaunchKernelGGL(transpose_bf16, dim3(32, 16, 2), dim3(256), 0, stream, Vb, Vt);
  hipLaunchKernelGGL(vblk32, dim3(128), dim3(256), 0, stream, Vb, Blk);
  hipLaunchKernelGGL(vsuffix32, dim3(8), dim3(256), 0, stream, Blk, Suf);
  hipLaunchKernelGGL(attn_v15, dim3(8, 32), dim3(1024), 0, stream,
                     Qb, Kb, Vt, AOP0, AOP1, AOP2, AOP3);
  hipLaunchKernelGGL(aocvt, dim3(2048), dim3(256), 0, stream,
                     AOP0, AOP1, AOP2, AOP3, Suf, AOb);
  hipLaunchKernelGGL((gemm_mfma<false>), dim3(8, 32, 1), dim3(256), 0, stream,
                     AOb, Wot, Wot, Wot, bo, bo, bo, (void*)out, (void*)out, (void*)out);
}

// Round 16
// 193.986 us; speedup vs baseline: 2.5809x; 1.0912x over previous
//
#include <hip/hip_runtime.h>
#include <hip/hip_bf16.h>

#define B_ 2
#define T_ 2048
#define D_ 1024
#define H_ 16

typedef __attribute__((ext_vector_type(8))) short bf16x8;
typedef __attribute__((ext_vector_type(4))) short bf16x4;
typedef __attribute__((ext_vector_type(4))) float f32x4;

__device__ __forceinline__ unsigned pack_bf16(float x, float y) {
  unsigned xb = __float_as_uint(x), yb = __float_as_uint(y);
  xb += 0x7fffu + ((xb >> 16) & 1u);
  yb += 0x7fffu + ((yb >> 16) & 1u);
  return (xb >> 16) | (yb & 0xffff0000u);
}
__device__ __forceinline__ unsigned short f2b(float x) {
  unsigned u = __float_as_uint(x);
  u += 0x7fffu + ((u >> 16) & 1u);
  return (unsigned short)(u >> 16);
}
__device__ __forceinline__ float blo(unsigned u) { return __uint_as_float(u << 16); }
__device__ __forceinline__ float bhi(unsigned u) { return __uint_as_float(u & 0xffff0000u); }

__device__ __forceinline__ void gld_lds16(const unsigned short* g, unsigned short* l) {
  __builtin_amdgcn_global_load_lds(
      (const __attribute__((address_space(1))) unsigned int*)g,
      (__attribute__((address_space(3))) unsigned int*)l, 16, 0, 0);
}

// ---------- weight transpose + convert: Wt[n][k] = bf16(W[k][n]), 4 weights ----------
__global__ __launch_bounds__(256) void wtrans(const float* __restrict__ W0, const float* __restrict__ W1,
                                              const float* __restrict__ W2, const float* __restrict__ W3,
                                              unsigned short* __restrict__ T0, unsigned short* __restrict__ T1,
                                              unsigned short* __restrict__ T2, unsigned short* __restrict__ T3) {
  const int z = blockIdx.z;
  const float* W = z == 0 ? W0 : z == 1 ? W1 : z == 2 ? W2 : W3;
  unsigned short* T = z == 0 ? T0 : z == 1 ? T1 : z == 2 ? T2 : T3;
  __shared__ unsigned short t[64][72];
  const int k0 = blockIdx.x << 6, n0 = blockIdx.y << 6;
  const int r = threadIdx.x >> 2, c16 = (threadIdx.x & 3) << 4;
#pragma unroll
  for (int e = 0; e < 4; ++e) {
    const float4 v = *(const float4*)&W[(size_t)(k0 + r) * 1024 + n0 + c16 + e * 4];
    t[r][c16 + e * 4 + 0] = f2b(v.x);
    t[r][c16 + e * 4 + 1] = f2b(v.y);
    t[r][c16 + e * 4 + 2] = f2b(v.z);
    t[r][c16 + e * 4 + 3] = f2b(v.w);
  }
  __syncthreads();
  unsigned short o[16];
#pragma unroll
  for (int e = 0; e < 16; ++e) o[e] = t[c16 + e][r];
  unsigned short* dst = &T[(size_t)(n0 + r) * 1024 + k0 + c16];
  *(uint4*)&dst[0] = *(uint4*)&o[0];
  *(uint4*)&dst[8] = *(uint4*)&o[8];
}

// ---------- x fp32 -> bf16 ----------
__global__ __launch_bounds__(256) void xconv(const float* __restrict__ x, unsigned short* __restrict__ xb) {
  const int i = (blockIdx.x * 256 + threadIdx.x) * 8;
  const float4 a = *(const float4*)&x[i];
  const float4 b = *(const float4*)&x[i + 4];
  uint4 o;
  o.x = pack_bf16(a.x, a.y);
  o.y = pack_bf16(a.z, a.w);
  o.z = pack_bf16(b.x, b.y);
  o.w = pack_bf16(b.z, b.w);
  *(uint4*)&xb[i] = o;
}

// ---------- bf16 MFMA GEMM: Y = A[M,1024] @ Bt[n][k]^T + bias ----------
template <bool BF16OUT>
__global__ __launch_bounds__(256) void gemm_mfma(const unsigned short* __restrict__ A,
                                                 const unsigned short* __restrict__ B0,
                                                 const unsigned short* __restrict__ B1,
                                                 const unsigned short* __restrict__ B2,
                                                 const float* __restrict__ bi0, const float* __restrict__ bi1,
                                                 const float* __restrict__ bi2,
                                                 void* __restrict__ Y0, void* __restrict__ Y1,
                                                 void* __restrict__ Y2) {
  const int z = blockIdx.z;
  const unsigned short* Bt = z == 0 ? B0 : z == 1 ? B1 : B2;
  const float* bias = z == 0 ? bi0 : z == 1 ? bi1 : bi2;
  void* Y = z == 0 ? Y0 : z == 1 ? Y1 : Y2;
  __shared__ unsigned short As[8192];
  __shared__ unsigned short Bs[8192];
  const int tid = threadIdx.x;
  const int m0 = blockIdx.y << 7, n0 = blockIdx.x << 7;
  const int w = tid >> 6, l = tid & 63, g = l >> 4, c = l & 15;
  const int wm = (w >> 1) << 6, wn = (w & 1) << 6;
  const int srow = tid >> 3;
  const int skel = ((tid & 7) ^ (srow & 7)) << 3;
  const unsigned short* ga = &A[(size_t)(m0 + srow) * 1024 + skel];
  const unsigned short* gb = &Bt[(size_t)(n0 + srow) * 1024 + skel];
  unsigned short* la = &As[tid << 3];
  unsigned short* lb = &Bs[tid << 3];
  f32x4 acc[4][4];
#pragma unroll
  for (int i = 0; i < 4; ++i)
#pragma unroll
    for (int j = 0; j < 4; ++j) acc[i][j] = {0.f, 0.f, 0.f, 0.f};
  for (int k0 = 0; k0 < 1024; k0 += 64) {
    __syncthreads();
#pragma unroll
    for (int a = 0; a < 4; ++a) {
      gld_lds16(ga + (size_t)(a << 5) * 1024 + k0, la + (a << 11));
      gld_lds16(gb + (size_t)(a << 5) * 1024 + k0, lb + (a << 11));
    }
    __syncthreads();
#pragma unroll
    for (int kc = 0; kc < 2; ++kc) {
      bf16x8 af[4], bfr[4];
#pragma unroll
      for (int mf = 0; mf < 4; ++mf) {
        const int m = wm + (mf << 4) + c;
        af[mf] = *(const bf16x8*)&As[((m << 6) + (kc << 5) + (g << 3)) ^ ((m & 7) << 3)];
      }
#pragma unroll
      for (int nf = 0; nf < 4; ++nf) {
        const int n = wn + (nf << 4) + c;
        bfr[nf] = *(const bf16x8*)&Bs[((n << 6) + (kc << 5) + (g << 3)) ^ ((n & 7) << 3)];
      }
#pragma unroll
      for (int mf = 0; mf < 4; ++mf)
#pragma unroll
        for (int nf = 0; nf < 4; ++nf)
          acc[mf][nf] = __builtin_amdgcn_mfma_f32_16x16x32_bf16(af[mf], bfr[nf], acc[mf][nf], 0, 0, 0);
    }
  }
#pragma unroll
  for (int nf = 0; nf < 4; ++nf) {
    const int n = n0 + wn + (nf << 4) + c;
    const float bb = bias[n];
#pragma unroll
    for (int mf = 0; mf < 4; ++mf) {
      const int mrow = m0 + wm + (mf << 4) + (g << 2);
#pragma unroll
      for (int r = 0; r < 4; ++r) {
        const float val = acc[mf][nf][r] + bb;
        if (BF16OUT)
          ((unsigned short*)Y)[((size_t)(mrow + r) << 10) + n] = f2b(val);
        else
          ((float*)Y)[((size_t)(mrow + r) << 10) + n] = val;
      }
    }
  }
}

// ---------- bf16 transpose: Vb [b][t][d] -> Vt [b][d][t] ----------
__global__ __launch_bounds__(256) void transpose_bf16(const unsigned short* __restrict__ Vb,
                                                      unsigned short* __restrict__ Vt) {
  __shared__ unsigned short tile[64][73];
  const int b = blockIdx.z;
  const int t0 = blockIdx.x << 6, d0 = blockIdx.y << 6;
  const int row = threadIdx.x >> 2, cq = (threadIdx.x & 3) << 4;
  const unsigned short* src = &Vb[((size_t)((b << 11) + t0 + row) << 10) + d0 + cq];
  const uint4 va = *(const uint4*)&src[0];
  const uint4 vb2 = *(const uint4*)&src[8];
  const unsigned in[8] = {va.x, va.y, va.z, va.w, vb2.x, vb2.y, vb2.z, vb2.w};
#pragma unroll
  for (int e = 0; e < 8; ++e) {
    tile[row][cq + 2 * e] = (unsigned short)in[e];
    tile[row][cq + 2 * e + 1] = (unsigned short)(in[e] >> 16);
  }
  __syncthreads();
  unsigned o[8];
#pragma unroll
  for (int e = 0; e < 8; ++e)
    o[e] = (unsigned)tile[cq + 2 * e][row] | ((unsigned)tile[cq + 2 * e + 1][row] << 16);
  unsigned short* dst = &Vt[((size_t)((b << 10) + d0 + row) << 11) + t0 + cq];
  uint4 lo, hi;
  lo.x = o[0]; lo.y = o[1]; lo.z = o[2]; lo.w = o[3];
  hi.x = o[4]; hi.y = o[5]; hi.z = o[6]; hi.w = o[7];
  *(uint4*)&dst[0] = lo;
  *(uint4*)&dst[8] = hi;
}

// ---------- per-32-row block sums of V ----------
__global__ __launch_bounds__(256) void vblk32(const unsigned short* __restrict__ Vb,
                                              float* __restrict__ Blk) {
  const int b = blockIdx.x >> 6, t = blockIdx.x & 63;
  const int d4 = threadIdx.x << 2;
  float s0 = 0.f, s1 = 0.f, s2 = 0.f, s3 = 0.f;
  for (int j = 0; j < 32; ++j) {
    const uint2 v = *(const uint2*)&Vb[((size_t)((b << 11) + (t << 5) + j) << 10) + d4];
    s0 += blo(v.x); s1 += bhi(v.x); s2 += blo(v.y); s3 += bhi(v.y);
  }
  float4 o = {s0, s1, s2, s3};
  *(float4*)&Blk[((size_t)((b << 6) + t) << 10) + d4] = o;
}

// ---------- suffix over 64 tiles ----------
__global__ __launch_bounds__(256) void vsuffix32(const float* __restrict__ Blk, float* __restrict__ Suf) {
  const int idx = blockIdx.x * 256 + threadIdx.x;
  const int b = idx >> 10, d = idx & 1023;
  float s = 0.f;
  Suf[((size_t)(b * 65 + 64) << 10) + d] = 0.f;
  for (int t = 63; t >= 0; --t) {
    s += Blk[((size_t)((b << 6) + t) << 10) + d];
    Suf[((size_t)(b * 65 + t) << 10) + d] = s;
  }
}

// ---------- attention v16: 16-j steps, double-buffered K/V staging pipeline ----------
// Block = (b,strip,qpair): 1024 thr = 2 i-subtiles x 8 head-pair waves, tiles (q,63-q).
// Per 16-j step: issue stage(nxt) -> QK(cur, 16x16x32) + exp -> f32 Sx write -> BAR ->
// Sx reduce + weights (uniform diag branch) + PV(cur, 16x16x16 k=j) -> BAR. Staging
// latency hides under compute. LDS: K 2x32KB + V 2x32KB + Sx 16KB = 144KB.
__global__ __launch_bounds__(1024, 4) void attn_v16(const unsigned short* __restrict__ Qb,
                                                    const unsigned short* __restrict__ Kb,
                                                    const unsigned short* __restrict__ Vt,
                                                    unsigned short* __restrict__ P0,
                                                    unsigned short* __restrict__ P1,
                                                    unsigned short* __restrict__ P2,
                                                    unsigned short* __restrict__ P3) {
  __shared__ unsigned short Ks[2][16 * 1024];  // 2 x 32 KB, XOR-swizzled rows
  __shared__ unsigned short Vs[2][1024 * 16];  // 2 x 32 KB, [d][16j], unit-XOR swizzle
  __shared__ f32x4 Sx[2][8][64];               // 16 KB f32 partial denominators

  const int combo = blockIdx.x;
  const int b = combo & 1, s = combo >> 1;
  const int qy = 63 - blockIdx.y;
  const int tid = threadIdx.x;
  const int w = tid >> 6, l = tid & 63, g = l >> 4, c = l & 15;
  const int isub = w >> 3, hp = w & 7;
  const float SC = 0.04508422f;  // log2(e)/32
  unsigned short* AOp = s == 0 ? P0 : s == 1 ? P1 : s == 2 ? P2 : P3;

  // staging address constants (per-lane invariants)
  const int krow0 = tid >> 7, kc8 = tid & 127;
  const int kscc = kc8 ^ (krow0 & 7);
  const int krow1 = (tid + 1024) >> 7, kc8b = tid & 127;  // same c8, row+8
  const int ksccb = kc8b ^ (krow1 & 7);

#pragma unroll
  for (int ph = 0; ph < 2; ++ph) {
    const int q = ph ? (63 - qy) : qy;
    const int nt16 = (q + 1) << 1;
    const int i0w = (q << 5) + (isub << 4);
    const int ib = i0w + c;

    const unsigned short* qbase =
        &Qb[((size_t)((b << 11) + i0w + c) << 10) + (hp << 7) + (g << 3)];
    bf16x8 qf[4];
    qf[0] = *(const bf16x8*)&qbase[0];
    qf[1] = *(const bf16x8*)&qbase[32];
    qf[2] = *(const bf16x8*)&qbase[64];
    qf[3] = *(const bf16x8*)&qbase[96];

    f32x4 acc[2][4];
#pragma unroll
    for (int hh = 0; hh < 2; ++hh)
#pragma unroll
      for (int cc = 0; cc < 4; ++cc) acc[hh][cc] = {0.f, 0.f, 0.f, 0.f};

#pragma unroll
    for (int e = 0; e < 2; ++e) {
      const int eh = e ? (7 - s) : s;
      const int lo = eh << 4;
      const int hi = (lo + 16) < nt16 ? (lo + 16) : nt16;
      if (lo >= hi) continue;

      // prologue: stage buffer 0
      {
        const int j0e = lo << 4;
        gld_lds16(&Kb[((size_t)((b << 11) + j0e + krow0) << 10) + (kscc << 3)], &Ks[0][tid << 3]);
        gld_lds16(&Kb[((size_t)((b << 11) + j0e + krow1) << 10) + (ksccb << 3)],
                  &Ks[0][(tid + 1024) << 3]);
#pragma unroll
        for (int kk = 0; kk < 2; ++kk) {
          const int qq = tid + (kk << 10);
          const int d = qq >> 1, jc = qq & 1;
          const int joff = ((jc << 1) ^ (((d >> 2) & 1) << 1)) << 2;
          gld_lds16(&Vt[(((size_t)((b << 10) + d)) << 11) + j0e + joff], &Vs[0][qq << 3]);
        }
      }
      __syncthreads();

      for (int ts = lo; ts < hi; ++ts) {
        const int cur = (ts - lo) & 1;
        // issue next step's staging (hides under this step's compute)
        if (ts + 1 < hi) {
          const int j0e = (ts + 1) << 4;
          gld_lds16(&Kb[((size_t)((b << 11) + j0e + krow0) << 10) + (kscc << 3)],
                    &Ks[cur ^ 1][tid << 3]);
          gld_lds16(&Kb[((size_t)((b << 11) + j0e + krow1) << 10) + (ksccb << 3)],
                    &Ks[cur ^ 1][(tid + 1024) << 3]);
#pragma unroll
          for (int kk = 0; kk < 2; ++kk) {
            const int qq = tid + (kk << 10);
            const int d = qq >> 1, jc = qq & 1;
            const int joff = ((jc << 1) ^ (((d >> 2) & 1) << 1)) << 2;
            gld_lds16(&Vt[(((size_t)((b << 10) + d)) << 11) + j0e + joff],
                      &Vs[cur ^ 1][qq << 3]);
          }
        }
        const int j0 = ts << 4;
        // QK from Ks[cur] + exp
        const int kx = c & 7;
        f32x4 ex[2];
        f32x4 ps = {0.f, 0.f, 0.f, 0.f};
#pragma unroll
        for (int hh = 0; hh < 2; ++hh) {
          const int hc = ((hp << 1) + hh) << 3;
          const bf16x8 k0 = *(const bf16x8*)&Ks[cur][((c << 7) + ((hc + g) ^ kx)) << 3];
          const bf16x8 k1 = *(const bf16x8*)&Ks[cur][((c << 7) + ((hc + 4 + g) ^ kx)) << 3];
          f32x4 a = {0.f, 0.f, 0.f, 0.f};
          a = __builtin_amdgcn_mfma_f32_16x16x32_bf16(k0, qf[2 * hh], a, 0, 0, 0);
          a = __builtin_amdgcn_mfma_f32_16x16x32_bf16(k1, qf[2 * hh + 1], a, 0, 0, 0);
#pragma unroll
          for (int r = 0; r < 4; ++r) ex[hh][r] = exp2f(a[r] * SC);
          ps += ex[hh];
        }
        Sx[isub][hp][l] = ps;
        __syncthreads();  // Sx ready (staging loads keep flying)
        f32x4 sum = Sx[isub][0][l];
#pragma unroll
        for (int d8 = 1; d8 < 8; ++d8) sum += Sx[isub][d8][l];
        f32x4 inv;
#pragma unroll
        for (int r = 0; r < 4; ++r) inv[r] = __builtin_amdgcn_rcpf(sum[r]);
        // weights (uniform diagonal branch)
        float wv[2][4];
        if (j0 + 15 <= i0w) {
#pragma unroll
          for (int hh = 0; hh < 2; ++hh)
#pragma unroll
            for (int r = 0; r < 4; ++r) wv[hh][r] = ex[hh][r] * inv[r];
        } else {
          const int jb = j0 + (g << 2);
#pragma unroll
          for (int hh = 0; hh < 2; ++hh)
#pragma unroll
            for (int r = 0; r < 4; ++r)
              wv[hh][r] = (jb + r > ib) ? 0.0625f : ex[hh][r] * inv[r];
        }
        // PV from Vs[cur] (k=16 via mfma_16x16x16 bf16)
#pragma unroll
        for (int hh = 0; hh < 2; ++hh) {
          union { bf16x4 v; unsigned u[2]; } pa;
          pa.u[0] = pack_bf16(wv[hh][0], wv[hh][1]);
          pa.u[1] = pack_bf16(wv[hh][2], wv[hh][3]);
#pragma unroll
          for (int cc = 0; cc < 4; ++cc) {
            const int d = (((hp << 1) + hh) << 6) + (cc << 4) + c;
            const int up = g ^ (((d >> 2) & 1) << 1);
            union { bf16x4 v; unsigned u[2]; } vf;
            *(uint2*)&vf = *(const uint2*)&Vs[cur][(d << 4) + (up << 2)];
            acc[hh][cc] =
                __builtin_amdgcn_mfma_f32_16x16x16bf16_1k(pa.v, vf.v, acc[hh][cc], 0, 0, 0);
          }
        }
        __syncthreads();  // cur reads done; safe to overwrite next iteration
      }
    }
    // write this (b, i-subtile) strip partial
#pragma unroll
    for (int hh = 0; hh < 2; ++hh)
#pragma unroll
      for (int cc = 0; cc < 4; ++cc) {
        const int d = (((hp << 1) + hh) << 6) + (cc << 4) + c;
#pragma unroll
        for (int r = 0; r < 4; ++r)
          AOp[((size_t)((b << 11) + i0w + (g << 2) + r) << 10) + d] = f2b(acc[hh][cc][r]);
      }
  }
}

// ---------- sum 4 bf16 partials + (1/16)*suffix -> bf16 ----------
__global__ __launch_bounds__(256) void aocvt(const unsigned short* __restrict__ P0,
                                             const unsigned short* __restrict__ P1,
                                             const unsigned short* __restrict__ P2,
                                             const unsigned short* __restrict__ P3,
                                             const float* __restrict__ Suf,
                                             unsigned short* __restrict__ AOb) {
  const int i = (blockIdx.x * 256 + threadIdx.x) << 3;
  const int m = i >> 10;
  const int b = m >> 11;
  const int sufidx = ((m & 2047) >> 5) + 1;
  const int d0 = i & 1023;
  const float* sp = &Suf[((size_t)(b * 65 + sufidx) << 10) + d0];
  const uint4 v0 = *(const uint4*)&P0[i];
  const uint4 v1 = *(const uint4*)&P1[i];
  const uint4 v2 = *(const uint4*)&P2[i];
  const uint4 v3 = *(const uint4*)&P3[i];
  const float4 s0 = *(const float4*)&sp[0];
  const float4 s1 = *(const float4*)&sp[4];
  uint4 o;
  o.x = pack_bf16(blo(v0.x) + blo(v1.x) + blo(v2.x) + blo(v3.x) + 0.0625f * s0.x,
                  bhi(v0.x) + bhi(v1.x) + bhi(v2.x) + bhi(v3.x) + 0.0625f * s0.y);
  o.y = pack_bf16(blo(v0.y) + blo(v1.y) + blo(v2.y) + blo(v3.y) + 0.0625f * s0.z,
                  bhi(v0.y) + bhi(v1.y) + bhi(v2.y) + bhi(v3.y) + 0.0625f * s0.w);
  o.z = pack_bf16(blo(v0.z) + blo(v1.z) + blo(v2.z) + blo(v3.z) + 0.0625f * s1.x,
                  bhi(v0.z) + bhi(v1.z) + bhi(v2.z) + bhi(v3.z) + 0.0625f * s1.y);
  o.w = pack_bf16(blo(v0.w) + blo(v1.w) + blo(v2.w) + blo(v3.w) + 0.0625f * s1.z,
                  bhi(v0.w) + bhi(v1.w) + bhi(v2.w) + bhi(v3.w) + 0.0625f * s1.w);
  *(uint4*)&AOb[i] = o;
}

extern "C" void kernel_launch(void* const* d_in, const int* in_sizes, int n_in,
                              void* d_out, int out_size, void* d_ws, size_t ws_size,
                              hipStream_t stream) {
  (void)in_sizes; (void)n_in; (void)out_size; (void)ws_size;
  const float* x = (const float*)d_in[0];
  const float* Wq = (const float*)d_in[1];
  const float* bq = (const float*)d_in[2];
  const float* Wk = (const float*)d_in[3];
  const float* bk = (const float*)d_in[4];
  const float* Wv = (const float*)d_in[5];
  const float* bv = (const float*)d_in[6];
  const float* Wo = (const float*)d_in[7];
  const float* bo = (const float*)d_in[8];
  float* out = (float*)d_out;
  char* ws = (char*)d_ws;

  const size_t MB = 1024 * 1024;
  unsigned short* xb  = (unsigned short*)(ws);            // 0-8MB; = AOP0 after projections
  unsigned short* Qb  = (unsigned short*)(ws + 8 * MB);   // 8-16; = AOb after attn
  unsigned short* Kb  = (unsigned short*)(ws + 16 * MB);  // 16-24
  unsigned short* Vb  = (unsigned short*)(ws + 24 * MB);  // 24-32; = AOP1 after transpose/vblk
  unsigned short* Vt  = (unsigned short*)(ws + 32 * MB);  // 32-40
  unsigned short* Wqt = (unsigned short*)(ws + 40 * MB);  // 40-42; Blk/Suf overlay after proj
  unsigned short* Wkt = (unsigned short*)(ws + 42 * MB);  // 42-44
  unsigned short* Wvt = (unsigned short*)(ws + 44 * MB);  // 44-46
  unsigned short* Wot = (unsigned short*)(ws + 46 * MB);  // 46-48
  unsigned short* AOP2 = (unsigned short*)(ws + 48 * MB); // 48-56
  unsigned short* AOP3 = (unsigned short*)(ws + 56 * MB); // 56-64
  float* Blk = (float*)(ws + 40 * MB);
  float* Suf = (float*)(ws + 40 * MB + 512 * 1024);
  unsigned short* AOP0 = xb;
  unsigned short* AOP1 = Vb;
  unsigned short* AOb = Qb;

  hipLaunchKernelGGL(wtrans, dim3(16, 16, 4), dim3(256), 0, stream,
                     Wq, Wk, Wv, Wo, Wqt, Wkt, Wvt, Wot);
  hipLaunchKernelGGL(xconv, dim3(2048), dim3(256), 0, stream, x, xb);
  hipLaunchKernelGGL((gemm_mfma<true>), dim3(8, 32, 3), dim3(256), 0, stream,
                     xb, Wqt, Wkt, Wvt, bq, bk, bv, (void*)Qb, (void*)Kb, (void*)Vb);
  hipLaunchKernelGGL(transpose_bf16, dim3(32, 16, 2), dim3(256), 0, stream, Vb, Vt);
  hipLaunchKernelGGL(vblk32, dim3(128), dim3(256), 0, stream, Vb, Blk);
  hipLaunchKernelGGL(vsuffix32, dim3(8), dim3(256), 0, stream, Blk, Suf);
  hipLaunchKernelGGL(attn_v16, dim3(8, 32), dim3(1024), 0, stream,
                     Qb, Kb, Vt, AOP0, AOP1, AOP2, AOP3);
  hipLaunchKernelGGL(aocvt, dim3(2048), dim3(256), 0, stream,
                     AOP0, AOP1, AOP2, AOP3, Suf, AOb);
  hipLaunchKernelGGL((gemm_mfma<false>), dim3(8, 32, 1), dim3(256), 0, stream,
                     AOb, Wot, Wot, Wot, bo, bo, bo, (void*)out, (void*)out, (void*)out);
}